// Round 9
// baseline (2048.770 us; speedup 1.0000x reference)
//
#include <hip/hip_runtime.h>
#include <hip/hip_bf16.h>

// Problem constants
#define NB 32
#define NT 1024
#define IH 180
#define IW 330
#define KSZ 37
#define H1 90
#define W1 165
#define H2 45
#define W2 82
#define PIX2 (H2*W2)          // 3690
#define CH1 32
#define CH2 64
#define CH3 128

#define NSTRIP 6
#define NCHUNK 8
#define STRIPE (IH*64)        // 11,520 per strip tile

// Per-batch f32 element counts
#define EL_HEAT (IH*IW)           // 59,400
#define EL_OUT1 (CH1*H1*W1)       // 475,200  (also hosts pp1)
#define EL_OUT2 (CH2*PIX2)        // 236,160
#define EL_MAP3 (CH3*PIX2)        // 472,320
#define EL_PX   (CH3*CH3)         // 16,384
// overlay plan: B hosts out1 then pp1; D hosts (scatter partials, fbuf) then pp2
#define EL_PER_BATCH (EL_HEAT + EL_OUT1 + EL_OUT2 + 2*EL_MAP3 + EL_PX) // 1,731,784

// folded-weight sizes (bf16 shorts): wT[tap][oc=128][ic]
#define WSH_A1 (9*128*64)         // 73,728
#define WSH_A2 (9*128*128)        // 147,456
#define WSH_TOT (2*WSH_A1 + 2*WSH_A2)  // 442,368 shorts

typedef __attribute__((ext_vector_type(8))) short short8;   // 8 bf16
typedef __attribute__((ext_vector_type(4))) float floatx4;

__device__ __forceinline__ short f2bf(float v) {
    __hip_bfloat16 h = __float2bfloat16(v);
    return *reinterpret_cast<short*>(&h);
}

// ---------------------------------------------------------------------------
// init m (heat max >=0 -> 0 bits) and pmm (min=+inf, max=0)
// ---------------------------------------------------------------------------
__global__ __launch_bounds__(256) void mm_init(unsigned* __restrict__ m_bits,
                                               unsigned* __restrict__ pmm_bits) {
    int i = threadIdx.x;
    if (i < 64) {
        m_bits[i] = 0u;
        pmm_bits[2 * i]     = 0x7F800000u;   // +inf
        pmm_bits[2 * i + 1] = 0u;
    }
}

// ---------------------------------------------------------------------------
// K1a: scatter stage 1. Grid (6 strips, 8 point-chunks, GB). One wave per
// point, lanes = patch columns, LDS atomics. Output: PRIVATE partial tile,
// plain coalesced stores — no global atomics.
// part[pc][lb][strip][STRIPE]
// ---------------------------------------------------------------------------
__global__ __launch_bounds__(256) void heat_scatter_part(const float* __restrict__ x_t,
                                                         float* __restrict__ part,
                                                         int b0, int gb) {
    const int strip = blockIdx.x;          // 0..5
    const int pc    = blockIdx.y;          // 0..7
    const int lb    = blockIdx.z;
    const int b = b0 + lb;
    const int c0 = strip * 64;
    const int cw = min(64, IW - c0);
    __shared__ float lds[STRIPE];
    __shared__ float k1n[64];
    const int tid = threadIdx.x;

    if (tid < 64) {
        float v = 0.0f;
        if (tid < KSZ) {
            float ax = (float)tid - 18.0f;
            v = expf(-ax * ax / 18.0f);    // 2*sigma^2 = 18
        }
        k1n[tid] = v;
    }
    for (int i = tid; i < STRIPE; i += 256) lds[i] = 0.0f;
    __syncthreads();
    if (tid == 0) {
        float s = 0.0f;
        for (int i = 0; i < KSZ; i++) s += k1n[i];
        float inv = 1.0f / s;
        for (int i = 0; i < KSZ; i++) k1n[i] *= inv;
    }
    __syncthreads();

    const int wave = tid >> 6;
    const int lane = tid & 63;
    const float kc = k1n[lane];

    const int pbeg = pc * (NT / NCHUNK);
    for (int p = pbeg + wave; p < pbeg + NT / NCHUNK; p += 4) {
        float x = x_t[(size_t)(b * NT + p) * 2 + 0];
        float y = x_t[(size_t)(b * NT + p) * 2 + 1];
        if (isnan(x) || isnan(y)) continue;
        int xp = IH - (int)((x - 30.0f) * 180.0f);
        int yp = (int)((y - 120.0f) * 165.0f);
        int xs = min(max(xp - 18, 0), IH - 36);
        int xe = min(max(xp + 18, 0), IH);
        int ys = min(max(yp - 18, 0), IW - 36);
        int ye = min(max(yp + 18, 0), IW);
        int nr = xe - xs, nc = ye - ys;
        if (nr <= 0 || nc <= 0) continue;
        int cbeg = max(ys, c0);
        int cend = min(ys + nc, c0 + cw);
        if (cbeg >= cend) continue;        // wave-uniform skip
        int col = ys + lane;
        if ((lane < nc) && (col >= c0) && (col < c0 + cw)) {
            int off = col - c0;
            for (int r = 0; r < nr; r++) {
                atomicAdd(&lds[(xs + r) * 64 + off], k1n[r] * kc);
            }
        }
    }
    __syncthreads();
    float* pb = part + (((size_t)pc * gb + lb) * NSTRIP + strip) * STRIPE;
    for (int i = tid; i < STRIPE; i += 256) pb[i] = lds[i];
}

// ---------------------------------------------------------------------------
// K1b: scatter stage 2 — sum the 8 partials per element, write heat, and
// fuse the per-batch max (block reduce + atomicMax). Covers all of heat.
// ---------------------------------------------------------------------------
__global__ __launch_bounds__(256) void heat_reduce(const float* __restrict__ part,
                                                   float* __restrict__ heat,
                                                   unsigned* __restrict__ m_bits,
                                                   int gb) {
    const int lb = blockIdx.y;
    const int idx = blockIdx.x * 256 + threadIdx.x;   // 0 .. 6*STRIPE-1
    float s = 0.0f;
    if (idx < NSTRIP * STRIPE) {
        const int strip = idx / STRIPE;
        const int i = idx % STRIPE;
#pragma unroll
        for (int pc = 0; pc < NCHUNK; pc++)
            s += part[(((size_t)pc * gb + lb) * NSTRIP + strip) * STRIPE + i];
        const int row = i / 64, col = i % 64;
        const int c = strip * 64 + col;
        if (c < IW) heat[(size_t)lb * EL_HEAT + row * IW + c] = s;
        else s = 0.0f;
    }
    __shared__ float red[256];
    red[threadIdx.x] = s;
    __syncthreads();
    for (int st = 128; st > 0; st >>= 1) {
        if (threadIdx.x < st) red[threadIdx.x] = fmaxf(red[threadIdx.x], red[threadIdx.x + st]);
        __syncthreads();
    }
    if (threadIdx.x == 0) atomicMax(&m_bits[lb], __float_as_uint(red[0]));
}

// ---------------------------------------------------------------------------
// K3: conv1(1->32) + BN + relu + pool, with fuse folded in
// ---------------------------------------------------------------------------
__global__ __launch_bounds__(256) void conv1_pool(const float* __restrict__ heat,
                                                  const float* __restrict__ image,
                                                  const float* __restrict__ m,
                                                  const float* __restrict__ w,
                                                  const float* __restrict__ cb,
                                                  const float* __restrict__ g,
                                                  const float* __restrict__ bb,
                                                  float* __restrict__ out1,
                                                  int b0, int gb) {
    __shared__ float ws_[CH1 * 9];
    __shared__ float bs_[CH1];
    const int tid = threadIdx.x;
    for (int i = tid; i < CH1 * 9; i += 256) {
        int oc = i / 9;
        ws_[i] = w[i] * g[oc];
    }
    if (tid < CH1) bs_[tid] = cb[tid] * g[tid] + bb[tid];
    __syncthreads();

    int t = blockIdx.x * 256 + tid;
    if (t >= gb * H1 * W1) return;
    int lb = t / (H1 * W1);
    int r = t % (H1 * W1);
    int py = r / W1, px = r % W1;
    const float s = 0.7f / (m[lb] + 1e-10f);
    const float* hb = heat + (size_t)lb * EL_HEAT;
    const float* ib = image + (size_t)(b0 + lb) * EL_HEAT;

    float v[4][4];
    int y0 = 2 * py - 1, x0 = 2 * px - 1;
#pragma unroll
    for (int i = 0; i < 4; i++) {
#pragma unroll
        for (int j = 0; j < 4; j++) {
            int y = y0 + i, x = x0 + j;
            float val = 0.0f;
            if (y >= 0 && y < IH && x >= 0 && x < IW) {
                size_t idx = (size_t)y * IW + x;
                val = s * hb[idx] + 0.3f * ib[idx];
            }
            v[i][j] = val;
        }
    }
    for (int oc = 0; oc < CH1; oc++) {
        float a00 = 0, a01 = 0, a10 = 0, a11 = 0;
        const float* wp = &ws_[oc * 9];
#pragma unroll
        for (int ky = 0; ky < 3; ky++) {
#pragma unroll
            for (int kx = 0; kx < 3; kx++) {
                float wv = wp[ky * 3 + kx];
                a00 += wv * v[ky][kx];
                a01 += wv * v[ky][kx + 1];
                a10 += wv * v[ky + 1][kx];
                a11 += wv * v[ky + 1][kx + 1];
            }
        }
        float bias = bs_[oc];
        a00 = fmaxf(a00 + bias, 0.0f);
        a01 = fmaxf(a01 + bias, 0.0f);
        a10 = fmaxf(a10 + bias, 0.0f);
        a11 = fmaxf(a11 + bias, 0.0f);
        float mx = fmaxf(fmaxf(a00, a01), fmaxf(a10, a11));
        out1[(((size_t)lb * CH1 + oc) * H1 + py) * W1 + px] = mx;
    }
}

// ---------------------------------------------------------------------------
// K4: conv2(32->64) + BN + relu + pool. Output CHANNEL-LAST: [lb][pixel][oc]
// ---------------------------------------------------------------------------
__global__ __launch_bounds__(256) void conv2_pool(const float* __restrict__ in,
                                                  const float* __restrict__ w,
                                                  const float* __restrict__ cb,
                                                  const float* __restrict__ g,
                                                  const float* __restrict__ bb,
                                                  float* __restrict__ out) {
    __shared__ float ws_[8 * CH1 * 9];
    __shared__ float bs_[8];
    const int tid = threadIdx.x;
    const int ocg = blockIdx.y;
    const int lb = blockIdx.z;
    for (int i = tid; i < 8 * CH1 * 9; i += 256) {
        int o = i / (CH1 * 9);
        int rest = i % (CH1 * 9);
        int oc = ocg * 8 + o;
        ws_[i] = w[(size_t)oc * CH1 * 9 + rest] * g[oc];
    }
    if (tid < 8) {
        int oc = ocg * 8 + tid;
        bs_[tid] = cb[oc] * g[oc] + bb[oc];
    }
    __syncthreads();

    int pid = blockIdx.x * 256 + tid;
    if (pid >= PIX2) return;
    int py = pid / W2, px = pid % W2;
    float acc[8][4];
#pragma unroll
    for (int o = 0; o < 8; o++)
#pragma unroll
        for (int q = 0; q < 4; q++) acc[o][q] = 0.0f;

    int y0 = 2 * py - 1, x0 = 2 * px - 1;
    for (int ic = 0; ic < CH1; ic++) {
        float v[4][4];
        const float* ip = in + ((size_t)lb * CH1 + ic) * H1 * W1;
#pragma unroll
        for (int i = 0; i < 4; i++) {
#pragma unroll
            for (int j = 0; j < 4; j++) {
                int y = y0 + i, x = x0 + j;
                v[i][j] = (y >= 0 && y < H1 && x >= 0 && x < W1) ? ip[(size_t)y * W1 + x] : 0.0f;
            }
        }
#pragma unroll
        for (int o = 0; o < 8; o++) {
            const float* wp = &ws_[(o * CH1 + ic) * 9];
#pragma unroll
            for (int ky = 0; ky < 3; ky++) {
#pragma unroll
                for (int kx = 0; kx < 3; kx++) {
                    float wv = wp[ky * 3 + kx];
                    acc[o][0] += wv * v[ky][kx];
                    acc[o][1] += wv * v[ky][kx + 1];
                    acc[o][2] += wv * v[ky + 1][kx];
                    acc[o][3] += wv * v[ky + 1][kx + 1];
                }
            }
        }
    }
    float* ob = out + ((size_t)lb * PIX2 + pid) * CH2 + ocg * 8;
#pragma unroll
    for (int o = 0; o < 8; o++) {
        float bias = bs_[o];
        float a0 = fmaxf(acc[o][0] + bias, 0.0f);
        float a1 = fmaxf(acc[o][1] + bias, 0.0f);
        float a2 = fmaxf(acc[o][2] + bias, 0.0f);
        float a3 = fmaxf(acc[o][3] + bias, 0.0f);
        ob[o] = fmaxf(fmaxf(a0, a1), fmaxf(a2, a3));
    }
}

// ---------------------------------------------------------------------------
// weight fold/transpose: wT[tap][oc][ic] = bf16(w[oc][ic][tap]*g[oc])
// ---------------------------------------------------------------------------
__global__ __launch_bounds__(256) void wfold_k(const float* __restrict__ w,
                                               const float* __restrict__ g,
                                               const float* __restrict__ cb,
                                               const float* __restrict__ bb,
                                               short* __restrict__ wT,
                                               float* __restrict__ bfold,
                                               int IC) {
    int i = blockIdx.x * 256 + threadIdx.x;
    int n = 9 * 128 * IC;
    if (i >= n) return;
    int tap = i / (128 * IC);
    int r = i % (128 * IC);
    int oc = r / IC;
    int ic = r % IC;
    wT[i] = f2bf(w[((size_t)oc * IC + ic) * 9 + tap] * g[oc]);
    if (tap == 0 && ic == 0) bfold[oc] = cb[oc] * g[oc] + bb[oc];
}

// ---------------------------------------------------------------------------
// K5-K8: 3x3 conv via bf16 MFMA, CHANNEL-LAST in/out
// ---------------------------------------------------------------------------
template <int IC, bool SIG>
__global__ __launch_bounds__(256) void conv3x3_mfma(const float* __restrict__ in,
                                                    const short* __restrict__ wT,
                                                    const float* __restrict__ bfold,
                                                    float* __restrict__ out) {
    const int xt = blockIdx.x;      // 0..5
    const int y  = blockIdx.y;      // 0..44
    const int lb = blockIdx.z;
    const int x0 = xt * 16;
    const int tid = threadIdx.x;
    const int wave = tid >> 6;
    const int lane = tid & 63;
    const int m = lane & 15;
    const int q = lane >> 4;

    constexpr int KC = 32;
    constexpr int NCH = IC / KC;
    constexpr int AP = 40;
    __shared__ __align__(16) short tileA[3 * 18 * AP];

    floatx4 acc0 = {0.f, 0.f, 0.f, 0.f};
    floatx4 acc1 = {0.f, 0.f, 0.f, 0.f};

    const float* inb = in + (size_t)lb * IC * PIX2;

    for (int c = 0; c < NCH; ++c) {
        const int ic0 = c * KC;
        {
            const int evec = 3 * 18 * (KC / 8);   // 216
            for (int e = tid; e < evec; e += 256) {
                int dy = e / (18 * (KC / 8));
                int r  = e % (18 * (KC / 8));
                int tx = r / (KC / 8);
                int i8 = r % (KC / 8);
                int yin = y + dy - 1;
                int xin = x0 + tx - 1;
                short8 hv = {0, 0, 0, 0, 0, 0, 0, 0};
                if (yin >= 0 && yin < H2 && xin >= 0 && xin < W2) {
                    const float* src = &inb[((size_t)yin * W2 + xin) * IC + ic0 + i8 * 8];
                    floatx4 f0 = *reinterpret_cast<const floatx4*>(src);
                    floatx4 f1 = *reinterpret_cast<const floatx4*>(src + 4);
                    hv[0] = f2bf(f0[0]); hv[1] = f2bf(f0[1]);
                    hv[2] = f2bf(f0[2]); hv[3] = f2bf(f0[3]);
                    hv[4] = f2bf(f1[0]); hv[5] = f2bf(f1[1]);
                    hv[6] = f2bf(f1[2]); hv[7] = f2bf(f1[3]);
                }
                *reinterpret_cast<short8*>(&tileA[(dy * 18 + tx) * AP + i8 * 8]) = hv;
            }
        }
        __syncthreads();

        const int oc0 = wave * 32 + m;
#pragma unroll
        for (int tap = 0; tap < 9; ++tap) {
            const int dy = tap / 3, dx = tap % 3;
            short8 af = *reinterpret_cast<const short8*>(
                &tileA[(dy * 18 + dx + m) * AP + q * 8]);
            const short* wt = wT + (size_t)tap * 128 * IC;
            short8 b0 = *reinterpret_cast<const short8*>(
                &wt[(size_t)oc0 * IC + ic0 + q * 8]);
            short8 b1 = *reinterpret_cast<const short8*>(
                &wt[(size_t)(oc0 + 16) * IC + ic0 + q * 8]);
            acc0 = __builtin_amdgcn_mfma_f32_16x16x32_bf16(af, b0, acc0, 0, 0, 0);
            acc1 = __builtin_amdgcn_mfma_f32_16x16x32_bf16(af, b1, acc1, 0, 0, 0);
        }
        __syncthreads();
    }

    float* outb = out + (size_t)lb * PIX2 * 128;
    const int oc0 = wave * 32 + m;
    const float bias0 = bfold[oc0];
    const float bias1 = bfold[oc0 + 16];
#pragma unroll
    for (int r = 0; r < 4; ++r) {
        int x = x0 + q * 4 + r;
        if (x < W2) {
            float z0 = acc0[r] + bias0;
            float z1 = acc1[r] + bias1;
            if (SIG) {
                z0 = 1.0f / (1.0f + expf(-z0));
                z1 = 1.0f / (1.0f + expf(-z1));
            } else {
                z0 = fmaxf(z0, 0.0f);
                z1 = fmaxf(z1, 0.0f);
            }
            float* op = &outb[((size_t)y * W2 + x) * 128];
            op[oc0] = z0;
            op[oc0 + 16] = z1;
        }
    }
}

// ---------------------------------------------------------------------------
// K9: per-batch min/max of p2 — multi-block + unsigned atomics (p2 >= 0)
// ---------------------------------------------------------------------------
__global__ __launch_bounds__(256) void pminmax(const float* __restrict__ p,
                                               unsigned* __restrict__ pmm_bits) {
    const int chunk = blockIdx.x;          // 0..31
    const int lb = blockIdx.y;
    const int n0 = chunk * (EL_MAP3 / 32);
    const int n1 = (chunk == 31) ? EL_MAP3 : n0 + (EL_MAP3 / 32);
    const float* pb = p + (size_t)lb * EL_MAP3;
    float mn = INFINITY, mx = 0.0f;
    for (int i = n0 + threadIdx.x; i < n1; i += 256) {
        float v = pb[i];
        mn = fminf(mn, v);
        mx = fmaxf(mx, v);
    }
    __shared__ float rmn[256], rmx[256];
    rmn[threadIdx.x] = mn; rmx[threadIdx.x] = mx;
    __syncthreads();
    for (int s = 128; s > 0; s >>= 1) {
        if (threadIdx.x < s) {
            rmn[threadIdx.x] = fminf(rmn[threadIdx.x], rmn[threadIdx.x + s]);
            rmx[threadIdx.x] = fmaxf(rmx[threadIdx.x], rmx[threadIdx.x + s]);
        }
        __syncthreads();
    }
    if (threadIdx.x == 0) {
        atomicMin(&pmm_bits[lb * 2],     __float_as_uint(rmn[0]));
        atomicMax(&pmm_bits[lb * 2 + 1], __float_as_uint(rmx[0]));
    }
}

// ---------------------------------------------------------------------------
// K10: p_map = sigmoid(10*((p-min)/max(max-min,1e-4) - 0.5))  (in place)
// ---------------------------------------------------------------------------
__global__ __launch_bounds__(256) void pmap_k(float* __restrict__ p,
                                              const float* __restrict__ mm,
                                              int n) {
    int i = blockIdx.x * 256 + threadIdx.x;
    if (i >= n) return;
    int lb = i / EL_MAP3;
    float mn = mm[lb * 2], mx = mm[lb * 2 + 1];
    float denom = fmaxf(mx - mn, 1e-4f);
    float v = (p[i] - mn) / denom;
    p[i] = 1.0f / (1.0f + expf(-10.0f * (v - 0.5f)));
}

// ---------------------------------------------------------------------------
// K11: px[p][c] = (1/3690) * sum_hw pm[hw][p] * fx[hw][c]   (channel-last)
// ---------------------------------------------------------------------------
__global__ __launch_bounds__(256) void einsum_k(const float* __restrict__ pm,
                                                const float* __restrict__ fx,
                                                float* __restrict__ px) {
    const int lb = blockIdx.z;
    const int pt = blockIdx.y;
    const int ct = blockIdx.x;
    __shared__ float As[64][33], Bs[64][33];
    const int tid = threadIdx.x;
    const int ty = tid / 16, tx = tid % 16;
    float acc00 = 0, acc01 = 0, acc10 = 0, acc11 = 0;
    const float* A = pm + (size_t)lb * EL_MAP3;
    const float* Bp = fx + (size_t)lb * EL_MAP3;
    for (int kk = 0; kk < PIX2; kk += 64) {
        for (int l = tid; l < 2048; l += 256) {
            int k = l >> 5, ch = l & 31;
            int gk = kk + k;
            float av = 0, bv = 0;
            if (gk < PIX2) {
                av = A[(size_t)gk * CH3 + pt * 32 + ch];
                bv = Bp[(size_t)gk * CH3 + ct * 32 + ch];
            }
            As[k][ch] = av;
            Bs[k][ch] = bv;
        }
        __syncthreads();
#pragma unroll
        for (int k = 0; k < 64; k++) {
            float a0 = As[k][2 * ty], a1 = As[k][2 * ty + 1];
            float b0 = Bs[k][2 * tx], b1 = Bs[k][2 * tx + 1];
            acc00 += a0 * b0; acc01 += a0 * b1;
            acc10 += a1 * b0; acc11 += a1 * b1;
        }
        __syncthreads();
    }
    const float inv = 1.0f / (float)PIX2;
    int p0 = pt * 32 + 2 * ty, c0 = ct * 32 + 2 * tx;
    px[((size_t)lb * CH3 + p0) * CH3 + c0] = acc00 * inv;
    px[((size_t)lb * CH3 + p0) * CH3 + c0 + 1] = acc01 * inv;
    px[((size_t)lb * CH3 + p0 + 1) * CH3 + c0] = acc10 * inv;
    px[((size_t)lb * CH3 + p0 + 1) * CH3 + c0 + 1] = acc11 * inv;
}

// ---------------------------------------------------------------------------
// K12: out[b0+lb,o] = sum_k px[lb,k]*fc_w[o,k] + fc_b[o]  (f32 output)
// ---------------------------------------------------------------------------
__global__ __launch_bounds__(256) void fc_k(const float* __restrict__ px,
                                            const float* __restrict__ w,
                                            const float* __restrict__ bias,
                                            float* __restrict__ out,
                                            int b0) {
    const int gw = blockIdx.x * 4 + (threadIdx.x >> 6);
    const int lane = threadIdx.x & 63;
    const int lb = gw >> 8;
    const int o = gw & 255;
    const float* xb = px + (size_t)lb * EL_PX;
    const float* wr = w + (size_t)o * EL_PX;
    float s = 0.0f;
    for (int k = lane; k < EL_PX; k += 64) s += xb[k] * wr[k];
#pragma unroll
    for (int off = 32; off > 0; off >>= 1) s += __shfl_down(s, off);
    if (lane == 0) out[(size_t)(b0 + lb) * 256 + o] = s + bias[o];
}

// ---------------------------------------------------------------------------
extern "C" void kernel_launch(void* const* d_in, const int* in_sizes, int n_in,
                              void* d_out, int out_size, void* d_ws, size_t ws_size,
                              hipStream_t stream) {
    const float* x_t   = (const float*)d_in[0];
    const float* image = (const float*)d_in[1];
    const float* c1_w  = (const float*)d_in[2];
    const float* c1_b  = (const float*)d_in[3];
    const float* bn1_g = (const float*)d_in[4];
    const float* bn1_b = (const float*)d_in[5];
    const float* c2_w  = (const float*)d_in[6];
    const float* c2_b  = (const float*)d_in[7];
    const float* bn2_g = (const float*)d_in[8];
    const float* bn2_b = (const float*)d_in[9];
    const float* a1_w  = (const float*)d_in[10];
    const float* a1_b  = (const float*)d_in[11];
    const float* abn1_g= (const float*)d_in[12];
    const float* abn1_b= (const float*)d_in[13];
    const float* a2_w  = (const float*)d_in[14];
    const float* a2_b  = (const float*)d_in[15];
    const float* abn2_g= (const float*)d_in[16];
    const float* abn2_b= (const float*)d_in[17];
    const float* p1_w  = (const float*)d_in[18];
    const float* p1_b  = (const float*)d_in[19];
    const float* pbn1_g= (const float*)d_in[20];
    const float* pbn1_b= (const float*)d_in[21];
    const float* p2_w  = (const float*)d_in[22];
    const float* p2_b  = (const float*)d_in[23];
    const float* pbn2_g= (const float*)d_in[24];
    const float* pbn2_b= (const float*)d_in[25];
    const float* fc_w  = (const float*)d_in[26];
    const float* fc_b  = (const float*)d_in[27];
    float* outp = (float*)d_out;

    // Fixed region: folded bf16 weights + biases
    float* ws = (float*)d_ws;
    short* wTa1 = (short*)ws;
    short* wTa2 = wTa1 + WSH_A1;
    short* wTp1 = wTa2 + WSH_A2;
    short* wTp2 = wTp1 + WSH_A1;
    float* bfa1 = ws + WSH_TOT / 2;
    float* bfa2 = bfa1 + 128;
    float* bfp1 = bfa2 + 128;
    float* bfp2 = bfp1 + 128;
    float* dyn  = bfp2 + 128;
    const size_t fixed_floats = WSH_TOT / 2 + 512;

    int GB = 32;
    while (GB > 1) {
        size_t need = ((size_t)GB * EL_PER_BATCH + fixed_floats + 256) * sizeof(float);
        if (need <= ws_size) break;
        GB >>= 1;
    }
    const int ngroups = NB / GB;

    // dynamic regions (overlays: B hosts out1 then pp1;
    //                   D+E host scatter partials, then D=fbuf->pp2, E=fx)
    float* heat = dyn;                                // EL_HEAT * GB
    float* m    = heat + (size_t)GB * EL_HEAT;        // 64
    float* regB = m + 64;                             // EL_OUT1 * GB
    float* regC = regB + (size_t)GB * EL_OUT1;        // EL_OUT2 * GB
    float* regD = regC + (size_t)GB * EL_OUT2;        // EL_MAP3 * GB
    float* regE = regD + (size_t)GB * EL_MAP3;        // EL_MAP3 * GB
    float* pmm  = regE + (size_t)GB * EL_MAP3;        // 128
    float* px   = pmm + 128;                          // EL_PX * GB
    float* out1 = regB;   // [lb][CH1][H1][W1]
    float* out2 = regC;   // [lb][PIX2][CH2] channel-last
    float* part = regD;   // scatter partials: NCHUNK*GB*6*STRIPE <= 2*EL_MAP3*GB
    float* fbuf = regD;   // [lb][PIX2][128] (partials dead after reduce)
    float* fx   = regE;
    float* pp1  = regB;   // (out1 dead)
    float* pp2  = regD;   // (fbuf dead)

    // fold weights
    wfold_k<<<(9 * 128 * CH2 + 255) / 256, 256, 0, stream>>>(a1_w, abn1_g, a1_b, abn1_b, wTa1, bfa1, CH2);
    wfold_k<<<(9 * 128 * CH3 + 255) / 256, 256, 0, stream>>>(a2_w, abn2_g, a2_b, abn2_b, wTa2, bfa2, CH3);
    wfold_k<<<(9 * 128 * CH2 + 255) / 256, 256, 0, stream>>>(p1_w, pbn1_g, p1_b, pbn1_b, wTp1, bfp1, CH2);
    wfold_k<<<(9 * 128 * CH3 + 255) / 256, 256, 0, stream>>>(p2_w, pbn2_g, p2_b, pbn2_b, wTp2, bfp2, CH3);

    const int ptiles = (PIX2 + 255) / 256;   // 15
    const int rblocks = (NSTRIP * STRIPE + 255) / 256;  // 270

    for (int gidx = 0; gidx < ngroups; ++gidx) {
        const int b0 = gidx * GB;
        mm_init<<<1, 256, 0, stream>>>((unsigned*)m, (unsigned*)pmm);
        // K1a: scatter into private partials (no global atomics)
        heat_scatter_part<<<dim3(NSTRIP, NCHUNK, GB), 256, 0, stream>>>(x_t, part, b0, GB);
        // K1b: reduce partials -> heat, fused per-batch max
        heat_reduce<<<dim3(rblocks, GB), 256, 0, stream>>>(part, heat, (unsigned*)m, GB);
        conv1_pool<<<(GB * H1 * W1 + 255) / 256, 256, 0, stream>>>(
            heat, image, m, c1_w, c1_b, bn1_g, bn1_b, out1, b0, GB);
        conv2_pool<<<dim3(ptiles, CH2 / 8, GB), 256, 0, stream>>>(
            out1, c2_w, c2_b, bn2_g, bn2_b, out2);
        conv3x3_mfma<CH2, false><<<dim3(6, H2, GB), 256, 0, stream>>>(out2, wTa1, bfa1, fbuf);
        conv3x3_mfma<CH3, true ><<<dim3(6, H2, GB), 256, 0, stream>>>(fbuf, wTa2, bfa2, fx);
        conv3x3_mfma<CH2, false><<<dim3(6, H2, GB), 256, 0, stream>>>(out2, wTp1, bfp1, pp1);
        conv3x3_mfma<CH3, false><<<dim3(6, H2, GB), 256, 0, stream>>>(pp1, wTp2, bfp2, pp2);
        pminmax<<<dim3(32, GB), 256, 0, stream>>>(pp2, (unsigned*)pmm);
        {
            int n = GB * EL_MAP3;
            pmap_k<<<(n + 255) / 256, 256, 0, stream>>>(pp2, pmm, n);
        }
        einsum_k<<<dim3(4, 4, GB), 256, 0, stream>>>(pp2, fx, px);
        fc_k<<<GB * 64, 256, 0, stream>>>(px, fc_w, fc_b, outp, b0);
    }
}

// Round 10
// 1724.549 us; speedup vs baseline: 1.1880x; 1.1880x over previous
//
#include <hip/hip_runtime.h>
#include <hip/hip_bf16.h>

// Problem constants
#define NB 32
#define NT 1024
#define IH 180
#define IW 330
#define KSZ 37
#define XBINS 181            // xp bins 0..180
#define H1 90
#define W1 165
#define H2 45
#define W2 82
#define PIX2 (H2*W2)          // 3690
#define KTOT PIX2             // einsum K
#define KPAD 3712             // padded K (16B-aligned bf16 rows)
#define CH1 32
#define CH2 64
#define CH3 128
#define NSTRIP 6

// Per-batch f32 element counts
#define EL_HEAT (IH*IW)           // 59,400
#define EL_OUT1 (CH1*H1*W1)       // 475,200
#define EL_OUT2 (CH2*PIX2)        // 236,160
#define EL_MAP3 (CH3*PIX2)        // 472,320
#define EL_FXBF (CH3*KPAD/2)      // 237,568 float slots (bf16 buffer)
#define EL_PX   (CH3*CH3)         // 16,384
// regB hosts out1 -> pp1 -> pmbf ; regD hosts G -> fbuf -> pp2 ; regE = fxbf
#define EL_PER_BATCH (EL_HEAT + EL_OUT1 + EL_OUT2 + EL_MAP3 + EL_FXBF + EL_PX) // 1,497,032

// folded-weight sizes (bf16 shorts): wT[tap][oc=128][ic]
#define WSH_A1 (9*128*64)
#define WSH_A2 (9*128*128)
#define WSH_TOT (2*WSH_A1 + 2*WSH_A2)

typedef __attribute__((ext_vector_type(8))) short short8;
typedef __attribute__((ext_vector_type(4))) float floatx4;

__device__ __forceinline__ short f2bf(float v) {
    __hip_bfloat16 h = __float2bfloat16(v);
    return *reinterpret_cast<short*>(&h);
}

// ---------------------------------------------------------------------------
// init m (heat max >=0 -> 0 bits) and pmm (min=+inf, max=0)
// ---------------------------------------------------------------------------
__global__ __launch_bounds__(256) void mm_init(unsigned* __restrict__ m_bits,
                                               unsigned* __restrict__ pmm_bits) {
    int i = threadIdx.x;
    if (i < 64) {
        m_bits[i] = 0u;
        pmm_bits[2 * i]     = 0x7F800000u;   // +inf
        pmm_bits[2 * i + 1] = 0u;
    }
}

// ---------------------------------------------------------------------------
// S1: separable scatter, stage 1 — column profiles into G[xp][Y].
// Grid (NSTRIP, GB). One wave per point; lanes = patch columns; ONE LDS-atomic
// wave-instruction per point (vs 37 before). Coords pre-staged in LDS.
// ---------------------------------------------------------------------------
__global__ __launch_bounds__(256) void heat_scatter_cols(const float* __restrict__ x_t,
                                                         float* __restrict__ G,
                                                         int b0) {
    const int strip = blockIdx.x;
    const int lb = blockIdx.y;
    const int b = b0 + lb;
    const int c0 = strip * 64;
    const int cw = min(64, IW - c0);
    __shared__ float g[XBINS * 64];        // 46,336 B
    __shared__ float k1n[64];
    __shared__ float2 pts[NT];             // 8 KB
    const int tid = threadIdx.x;

    if (tid < 64) {
        float v = 0.0f;
        if (tid < KSZ) {
            float ax = (float)tid - 18.0f;
            v = expf(-ax * ax / 18.0f);    // 2*sigma^2 = 18
        }
        k1n[tid] = v;
    }
    for (int i = tid; i < XBINS * 64; i += 256) g[i] = 0.0f;
    {
        const float2* xb = (const float2*)x_t + (size_t)b * NT;
        for (int i = tid; i < NT; i += 256) pts[i] = xb[i];
    }
    __syncthreads();
    if (tid == 0) {
        float s = 0.0f;
        for (int i = 0; i < KSZ; i++) s += k1n[i];
        float inv = 1.0f / s;
        for (int i = 0; i < KSZ; i++) k1n[i] *= inv;
    }
    __syncthreads();

    const int wave = tid >> 6;
    const int lane = tid & 63;
    const float kc = k1n[lane];

    for (int p = wave; p < NT; p += 4) {
        float x = pts[p].x, y = pts[p].y;
        if (isnan(x) || isnan(y)) continue;
        int xp = IH - (int)((x - 30.0f) * 180.0f);
        xp = min(max(xp, 0), 180);
        int yp = (int)((y - 120.0f) * 165.0f);
        int ys = min(max(yp - 18, 0), IW - 36);
        int ye = min(max(yp + 18, 0), IW);
        int nc = ye - ys;
        int col = ys + lane;
        if (lane < nc && col >= c0 && col < c0 + cw)
            atomicAdd(&g[xp * 64 + col - c0], kc);
    }
    __syncthreads();
    for (int i = tid; i < XBINS * cw; i += 256) {
        int row = i / cw, col = i % cw;
        G[((size_t)lb * XBINS + row) * IW + c0 + col] = g[row * 64 + col];
    }
}

// ---------------------------------------------------------------------------
// S2: row-combine — heat[X][Y] = sum_{xp in [lo,hi]} k1n[X-xs(xp)]*G[xp][Y],
// fused per-batch max (atomicMax on bits; heat >= 0).
// ---------------------------------------------------------------------------
__global__ __launch_bounds__(256) void heat_rowcombine(const float* __restrict__ G,
                                                       float* __restrict__ heat,
                                                       unsigned* __restrict__ m_bits) {
    const int lb = blockIdx.y;
    const int tid = threadIdx.x;
    __shared__ float k1n[64];
    if (tid < 64) {
        float v = 0.0f;
        if (tid < KSZ) {
            float ax = (float)tid - 18.0f;
            v = expf(-ax * ax / 18.0f);
        }
        k1n[tid] = v;
    }
    __syncthreads();
    if (tid == 0) {
        float s = 0.0f;
        for (int i = 0; i < KSZ; i++) s += k1n[i];
        float inv = 1.0f / s;
        for (int i = 0; i < KSZ; i++) k1n[i] *= inv;
    }
    __syncthreads();

    const int idx = blockIdx.x * 256 + tid;
    float s = 0.0f;
    if (idx < EL_HEAT) {
        int X = idx / IW, Y = idx % IW;
        int lo = max(0, X - 17);
        int hi = (X >= IH - 36) ? 180 : X + 18;
        const float* Gb = G + (size_t)lb * XBINS * IW + Y;
        for (int xp = lo; xp <= hi; ++xp) {
            int xs = min(max(xp - 18, 0), IH - 36);
            s += k1n[X - xs] * Gb[(size_t)xp * IW];
        }
        heat[(size_t)lb * EL_HEAT + idx] = s;
    }
    __shared__ float red[256];
    red[tid] = s;
    __syncthreads();
    for (int st = 128; st > 0; st >>= 1) {
        if (tid < st) red[tid] = fmaxf(red[tid], red[tid + st]);
        __syncthreads();
    }
    if (tid == 0) atomicMax(&m_bits[lb], __float_as_uint(red[0]));
}

// ---------------------------------------------------------------------------
// K3: conv1(1->32) + BN + relu + pool, fuse folded in
// ---------------------------------------------------------------------------
__global__ __launch_bounds__(256) void conv1_pool(const float* __restrict__ heat,
                                                  const float* __restrict__ image,
                                                  const float* __restrict__ m,
                                                  const float* __restrict__ w,
                                                  const float* __restrict__ cb,
                                                  const float* __restrict__ g,
                                                  const float* __restrict__ bb,
                                                  float* __restrict__ out1,
                                                  int b0, int gb) {
    __shared__ float ws_[CH1 * 9];
    __shared__ float bs_[CH1];
    const int tid = threadIdx.x;
    for (int i = tid; i < CH1 * 9; i += 256) {
        int oc = i / 9;
        ws_[i] = w[i] * g[oc];
    }
    if (tid < CH1) bs_[tid] = cb[tid] * g[tid] + bb[tid];
    __syncthreads();

    int t = blockIdx.x * 256 + tid;
    if (t >= gb * H1 * W1) return;
    int lb = t / (H1 * W1);
    int r = t % (H1 * W1);
    int py = r / W1, px = r % W1;
    const float s = 0.7f / (m[lb] + 1e-10f);
    const float* hb = heat + (size_t)lb * EL_HEAT;
    const float* ib = image + (size_t)(b0 + lb) * EL_HEAT;

    float v[4][4];
    int y0 = 2 * py - 1, x0 = 2 * px - 1;
#pragma unroll
    for (int i = 0; i < 4; i++) {
#pragma unroll
        for (int j = 0; j < 4; j++) {
            int y = y0 + i, x = x0 + j;
            float val = 0.0f;
            if (y >= 0 && y < IH && x >= 0 && x < IW) {
                size_t idx = (size_t)y * IW + x;
                val = s * hb[idx] + 0.3f * ib[idx];
            }
            v[i][j] = val;
        }
    }
    for (int oc = 0; oc < CH1; oc++) {
        float a00 = 0, a01 = 0, a10 = 0, a11 = 0;
        const float* wp = &ws_[oc * 9];
#pragma unroll
        for (int ky = 0; ky < 3; ky++) {
#pragma unroll
            for (int kx = 0; kx < 3; kx++) {
                float wv = wp[ky * 3 + kx];
                a00 += wv * v[ky][kx];
                a01 += wv * v[ky][kx + 1];
                a10 += wv * v[ky + 1][kx];
                a11 += wv * v[ky + 1][kx + 1];
            }
        }
        float bias = bs_[oc];
        a00 = fmaxf(a00 + bias, 0.0f);
        a01 = fmaxf(a01 + bias, 0.0f);
        a10 = fmaxf(a10 + bias, 0.0f);
        a11 = fmaxf(a11 + bias, 0.0f);
        float mx = fmaxf(fmaxf(a00, a01), fmaxf(a10, a11));
        out1[(((size_t)lb * CH1 + oc) * H1 + py) * W1 + px] = mx;
    }
}

// ---------------------------------------------------------------------------
// K4: conv2(32->64) + BN + relu + pool. Output CHANNEL-LAST [lb][pixel][oc]
// ---------------------------------------------------------------------------
__global__ __launch_bounds__(256) void conv2_pool(const float* __restrict__ in,
                                                  const float* __restrict__ w,
                                                  const float* __restrict__ cb,
                                                  const float* __restrict__ g,
                                                  const float* __restrict__ bb,
                                                  float* __restrict__ out) {
    __shared__ float ws_[8 * CH1 * 9];
    __shared__ float bs_[8];
    const int tid = threadIdx.x;
    const int ocg = blockIdx.y;
    const int lb = blockIdx.z;
    for (int i = tid; i < 8 * CH1 * 9; i += 256) {
        int o = i / (CH1 * 9);
        int rest = i % (CH1 * 9);
        int oc = ocg * 8 + o;
        ws_[i] = w[(size_t)oc * CH1 * 9 + rest] * g[oc];
    }
    if (tid < 8) {
        int oc = ocg * 8 + tid;
        bs_[tid] = cb[oc] * g[oc] + bb[oc];
    }
    __syncthreads();

    int pid = blockIdx.x * 256 + tid;
    if (pid >= PIX2) return;
    int py = pid / W2, px = pid % W2;
    float acc[8][4];
#pragma unroll
    for (int o = 0; o < 8; o++)
#pragma unroll
        for (int q = 0; q < 4; q++) acc[o][q] = 0.0f;

    int y0 = 2 * py - 1, x0 = 2 * px - 1;
    for (int ic = 0; ic < CH1; ic++) {
        float v[4][4];
        const float* ip = in + ((size_t)lb * CH1 + ic) * H1 * W1;
#pragma unroll
        for (int i = 0; i < 4; i++) {
#pragma unroll
            for (int j = 0; j < 4; j++) {
                int y = y0 + i, x = x0 + j;
                v[i][j] = (y >= 0 && y < H1 && x >= 0 && x < W1) ? ip[(size_t)y * W1 + x] : 0.0f;
            }
        }
#pragma unroll
        for (int o = 0; o < 8; o++) {
            const float* wp = &ws_[(o * CH1 + ic) * 9];
#pragma unroll
            for (int ky = 0; ky < 3; ky++) {
#pragma unroll
                for (int kx = 0; kx < 3; kx++) {
                    float wv = wp[ky * 3 + kx];
                    acc[o][0] += wv * v[ky][kx];
                    acc[o][1] += wv * v[ky][kx + 1];
                    acc[o][2] += wv * v[ky + 1][kx];
                    acc[o][3] += wv * v[ky + 1][kx + 1];
                }
            }
        }
    }
    float* ob = out + ((size_t)lb * PIX2 + pid) * CH2 + ocg * 8;
#pragma unroll
    for (int o = 0; o < 8; o++) {
        float bias = bs_[o];
        float a0 = fmaxf(acc[o][0] + bias, 0.0f);
        float a1 = fmaxf(acc[o][1] + bias, 0.0f);
        float a2 = fmaxf(acc[o][2] + bias, 0.0f);
        float a3 = fmaxf(acc[o][3] + bias, 0.0f);
        ob[o] = fmaxf(fmaxf(a0, a1), fmaxf(a2, a3));
    }
}

// ---------------------------------------------------------------------------
// weight fold/transpose: wT[tap][oc][ic] = bf16(w[oc][ic][tap]*g[oc])
// ---------------------------------------------------------------------------
__global__ __launch_bounds__(256) void wfold_k(const float* __restrict__ w,
                                               const float* __restrict__ g,
                                               const float* __restrict__ cb,
                                               const float* __restrict__ bb,
                                               short* __restrict__ wT,
                                               float* __restrict__ bfold,
                                               int IC) {
    int i = blockIdx.x * 256 + threadIdx.x;
    int n = 9 * 128 * IC;
    if (i >= n) return;
    int tap = i / (128 * IC);
    int r = i % (128 * IC);
    int oc = r / IC;
    int ic = r % IC;
    wT[i] = f2bf(w[((size_t)oc * IC + ic) * 9 + tap] * g[oc]);
    if (tap == 0 && ic == 0) bfold[oc] = cb[oc] * g[oc] + bb[oc];
}

// ---------------------------------------------------------------------------
// K5-K8: 3x3 conv via bf16 MFMA, channel-last input.
// OM: 0 = ch-last f32 out, 1 = ch-first f32 out, 2 = ch-first bf16 out (KPAD)
// ---------------------------------------------------------------------------
template <int IC, bool SIG, int OM>
__global__ __launch_bounds__(256) void conv3x3_mfma(const float* __restrict__ in,
                                                    const short* __restrict__ wT,
                                                    const float* __restrict__ bfold,
                                                    void* __restrict__ outv) {
    const int xt = blockIdx.x;      // 0..5
    const int y  = blockIdx.y;      // 0..44
    const int lb = blockIdx.z;
    const int x0 = xt * 16;
    const int tid = threadIdx.x;
    const int wave = tid >> 6;
    const int lane = tid & 63;
    const int mm = lane & 15;
    const int q = lane >> 4;

    constexpr int KC = 32;
    constexpr int NCH = IC / KC;
    constexpr int AP = 40;
    __shared__ __align__(16) short tileA[3 * 18 * AP];

    floatx4 acc0 = {0.f, 0.f, 0.f, 0.f};
    floatx4 acc1 = {0.f, 0.f, 0.f, 0.f};

    const float* inb = in + (size_t)lb * IC * PIX2;

    for (int c = 0; c < NCH; ++c) {
        const int ic0 = c * KC;
        {
            const int evec = 3 * 18 * (KC / 8);   // 216
            for (int e = tid; e < evec; e += 256) {
                int dy = e / (18 * (KC / 8));
                int r  = e % (18 * (KC / 8));
                int tx = r / (KC / 8);
                int i8 = r % (KC / 8);
                int yin = y + dy - 1;
                int xin = x0 + tx - 1;
                short8 hv = {0, 0, 0, 0, 0, 0, 0, 0};
                if (yin >= 0 && yin < H2 && xin >= 0 && xin < W2) {
                    const float* src = &inb[((size_t)yin * W2 + xin) * IC + ic0 + i8 * 8];
                    floatx4 f0 = *reinterpret_cast<const floatx4*>(src);
                    floatx4 f1 = *reinterpret_cast<const floatx4*>(src + 4);
                    hv[0] = f2bf(f0[0]); hv[1] = f2bf(f0[1]);
                    hv[2] = f2bf(f0[2]); hv[3] = f2bf(f0[3]);
                    hv[4] = f2bf(f1[0]); hv[5] = f2bf(f1[1]);
                    hv[6] = f2bf(f1[2]); hv[7] = f2bf(f1[3]);
                }
                *reinterpret_cast<short8*>(&tileA[(dy * 18 + tx) * AP + i8 * 8]) = hv;
            }
        }
        __syncthreads();

        const int oc0 = wave * 32 + mm;
#pragma unroll
        for (int tap = 0; tap < 9; ++tap) {
            const int dy = tap / 3, dx = tap % 3;
            short8 af = *reinterpret_cast<const short8*>(
                &tileA[(dy * 18 + dx + mm) * AP + q * 8]);
            const short* wt = wT + (size_t)tap * 128 * IC;
            short8 b0 = *reinterpret_cast<const short8*>(
                &wt[(size_t)oc0 * IC + ic0 + q * 8]);
            short8 b1 = *reinterpret_cast<const short8*>(
                &wt[(size_t)(oc0 + 16) * IC + ic0 + q * 8]);
            acc0 = __builtin_amdgcn_mfma_f32_16x16x32_bf16(af, b0, acc0, 0, 0, 0);
            acc1 = __builtin_amdgcn_mfma_f32_16x16x32_bf16(af, b1, acc1, 0, 0, 0);
        }
        __syncthreads();
    }

    const int oc0 = wave * 32 + mm;
    const float bias0 = bfold[oc0];
    const float bias1 = bfold[oc0 + 16];
#pragma unroll
    for (int r = 0; r < 4; ++r) {
        int x = x0 + q * 4 + r;
        if (x < W2) {
            float z0 = acc0[r] + bias0;
            float z1 = acc1[r] + bias1;
            if (SIG) {
                z0 = 1.0f / (1.0f + expf(-z0));
                z1 = 1.0f / (1.0f + expf(-z1));
            } else {
                z0 = fmaxf(z0, 0.0f);
                z1 = fmaxf(z1, 0.0f);
            }
            int hw = y * W2 + x;
            if (OM == 0) {
                float* op = (float*)outv + ((size_t)lb * PIX2 + hw) * 128;
                op[oc0] = z0;
                op[oc0 + 16] = z1;
            } else if (OM == 1) {
                float* op = (float*)outv + (size_t)lb * EL_MAP3;
                op[(size_t)oc0 * PIX2 + hw] = z0;
                op[(size_t)(oc0 + 16) * PIX2 + hw] = z1;
            } else {
                short* op = (short*)outv + (size_t)lb * 128 * KPAD;
                op[(size_t)oc0 * KPAD + hw] = f2bf(z0);
                op[(size_t)(oc0 + 16) * KPAD + hw] = f2bf(z1);
            }
        }
    }
}

// ---------------------------------------------------------------------------
// K9: per-batch min/max of p2 (flat) — multi-block + unsigned atomics (p2>=0)
// ---------------------------------------------------------------------------
__global__ __launch_bounds__(256) void pminmax(const float* __restrict__ p,
                                               unsigned* __restrict__ pmm_bits) {
    const int chunk = blockIdx.x;          // 0..31
    const int lb = blockIdx.y;
    const int n0 = chunk * (EL_MAP3 / 32);
    const int n1 = (chunk == 31) ? EL_MAP3 : n0 + (EL_MAP3 / 32);
    const float* pb = p + (size_t)lb * EL_MAP3;
    float mn = INFINITY, mx = 0.0f;
    for (int i = n0 + threadIdx.x; i < n1; i += 256) {
        float v = pb[i];
        mn = fminf(mn, v);
        mx = fmaxf(mx, v);
    }
    __shared__ float rmn[256], rmx[256];
    rmn[threadIdx.x] = mn; rmx[threadIdx.x] = mx;
    __syncthreads();
    for (int s = 128; s > 0; s >>= 1) {
        if (threadIdx.x < s) {
            rmn[threadIdx.x] = fminf(rmn[threadIdx.x], rmn[threadIdx.x + s]);
            rmx[threadIdx.x] = fmaxf(rmx[threadIdx.x], rmx[threadIdx.x + s]);
        }
        __syncthreads();
    }
    if (threadIdx.x == 0) {
        atomicMin(&pmm_bits[lb * 2],     __float_as_uint(rmn[0]));
        atomicMax(&pmm_bits[lb * 2 + 1], __float_as_uint(rmx[0]));
    }
}

// ---------------------------------------------------------------------------
// K10: p_map -> bf16 [p][KPAD] (ch-first). grid (15, 128, GB)
// ---------------------------------------------------------------------------
__global__ __launch_bounds__(256) void pmap_bf(const float* __restrict__ p,
                                               const float* __restrict__ mm,
                                               short* __restrict__ pmb) {
    const int hwi = blockIdx.x * 256 + threadIdx.x;
    const int ch = blockIdx.y;
    const int lb = blockIdx.z;
    if (hwi >= PIX2) return;
    float mn = mm[lb * 2], mx = mm[lb * 2 + 1];
    float denom = fmaxf(mx - mn, 1e-4f);
    float v = (p[(size_t)lb * EL_MAP3 + (size_t)ch * PIX2 + hwi] - mn) / denom;
    float sg = 1.0f / (1.0f + expf(-10.0f * (v - 0.5f)));
    pmb[(size_t)lb * 128 * KPAD + (size_t)ch * KPAD + hwi] = f2bf(sg);
}

// ---------------------------------------------------------------------------
// K11: einsum via bf16 MFMA. A = pm[p][KPAD], B = fx[c][KPAD]; C[p][c].
// Grid (8 m-slices of 16 p, GB). Wave w owns n-tiles {2w, 2w+1}.
// ---------------------------------------------------------------------------
__global__ __launch_bounds__(256) void einsum_mfma(const short* __restrict__ pm,
                                                   const short* __restrict__ fxb,
                                                   float* __restrict__ px) {
    const int ms = blockIdx.x;   // 0..7
    const int lb = blockIdx.y;
    const int tid = threadIdx.x;
    const int wave = tid >> 6, lane = tid & 63;
    const int mm = lane & 15, q = lane >> 4;
    constexpr int KC = 64;
    constexpr int AP = 72;
    __shared__ __align__(16) short As[16 * AP];
    __shared__ __align__(16) short Bs[128 * AP];
    floatx4 acc0 = {0.f, 0.f, 0.f, 0.f};
    floatx4 acc1 = {0.f, 0.f, 0.f, 0.f};
    const short* Ab = pm + (size_t)lb * 128 * KPAD + (size_t)ms * 16 * KPAD;
    const short* Bb = fxb + (size_t)lb * 128 * KPAD;
    const int nch = (KTOT + KC - 1) / KC;   // 58

    for (int c = 0; c < nch; ++c) {
        const int kk = c * KC;
        for (int e = tid; e < 1152; e += 256) {
            const short* src; short* dst; int i8;
            if (e < 128) { int row = e >> 3; i8 = e & 7; src = Ab + (size_t)row * KPAD; dst = &As[row * AP]; }
            else { int e2 = e - 128; int row = e2 >> 3; i8 = e2 & 7; src = Bb + (size_t)row * KPAD; dst = &Bs[row * AP]; }
            int k = kk + i8 * 8;
            short8 v;
            if (k + 8 <= KTOT) {
                v = *reinterpret_cast<const short8*>(src + k);
            } else {
#pragma unroll
                for (int j = 0; j < 8; ++j) v[j] = (k + j < KTOT) ? src[k + j] : (short)0;
            }
            *reinterpret_cast<short8*>(dst + i8 * 8) = v;
        }
        __syncthreads();
#pragma unroll
        for (int ks = 0; ks < 2; ++ks) {
            short8 af = *reinterpret_cast<const short8*>(&As[mm * AP + ks * 32 + q * 8]);
            short8 b0 = *reinterpret_cast<const short8*>(&Bs[(wave * 32 + mm) * AP + ks * 32 + q * 8]);
            short8 b1 = *reinterpret_cast<const short8*>(&Bs[(wave * 32 + 16 + mm) * AP + ks * 32 + q * 8]);
            acc0 = __builtin_amdgcn_mfma_f32_16x16x32_bf16(af, b0, acc0, 0, 0, 0);
            acc1 = __builtin_amdgcn_mfma_f32_16x16x32_bf16(af, b1, acc1, 0, 0, 0);
        }
        __syncthreads();
    }
    const float inv = 1.0f / (float)KTOT;
    float* pxb = px + (size_t)lb * EL_PX + (size_t)ms * 16 * 128;
    const int c0 = wave * 32 + mm;
#pragma unroll
    for (int r = 0; r < 4; ++r) {
        int p = q * 4 + r;
        pxb[p * 128 + c0] = acc0[r] * inv;
        pxb[p * 128 + c0 + 16] = acc1[r] * inv;
    }
}

// ---------------------------------------------------------------------------
// K12: out[b0+lb,o] = sum_k px[lb,k]*fc_w[o,k] + fc_b[o]  (f32 output)
// ---------------------------------------------------------------------------
__global__ __launch_bounds__(256) void fc_k(const float* __restrict__ px,
                                            const float* __restrict__ w,
                                            const float* __restrict__ bias,
                                            float* __restrict__ out,
                                            int b0) {
    const int gw = blockIdx.x * 4 + (threadIdx.x >> 6);
    const int lane = threadIdx.x & 63;
    const int lb = gw >> 8;
    const int o = gw & 255;
    const float* xb = px + (size_t)lb * EL_PX;
    const float* wr = w + (size_t)o * EL_PX;
    float s = 0.0f;
    for (int k = lane; k < EL_PX; k += 64) s += xb[k] * wr[k];
#pragma unroll
    for (int off = 32; off > 0; off >>= 1) s += __shfl_down(s, off);
    if (lane == 0) out[(size_t)(b0 + lb) * 256 + o] = s + bias[o];
}

// ---------------------------------------------------------------------------
extern "C" void kernel_launch(void* const* d_in, const int* in_sizes, int n_in,
                              void* d_out, int out_size, void* d_ws, size_t ws_size,
                              hipStream_t stream) {
    const float* x_t   = (const float*)d_in[0];
    const float* image = (const float*)d_in[1];
    const float* c1_w  = (const float*)d_in[2];
    const float* c1_b  = (const float*)d_in[3];
    const float* bn1_g = (const float*)d_in[4];
    const float* bn1_b = (const float*)d_in[5];
    const float* c2_w  = (const float*)d_in[6];
    const float* c2_b  = (const float*)d_in[7];
    const float* bn2_g = (const float*)d_in[8];
    const float* bn2_b = (const float*)d_in[9];
    const float* a1_w  = (const float*)d_in[10];
    const float* a1_b  = (const float*)d_in[11];
    const float* abn1_g= (const float*)d_in[12];
    const float* abn1_b= (const float*)d_in[13];
    const float* a2_w  = (const float*)d_in[14];
    const float* a2_b  = (const float*)d_in[15];
    const float* abn2_g= (const float*)d_in[16];
    const float* abn2_b= (const float*)d_in[17];
    const float* p1_w  = (const float*)d_in[18];
    const float* p1_b  = (const float*)d_in[19];
    const float* pbn1_g= (const float*)d_in[20];
    const float* pbn1_b= (const float*)d_in[21];
    const float* p2_w  = (const float*)d_in[22];
    const float* p2_b  = (const float*)d_in[23];
    const float* pbn2_g= (const float*)d_in[24];
    const float* pbn2_b= (const float*)d_in[25];
    const float* fc_w  = (const float*)d_in[26];
    const float* fc_b  = (const float*)d_in[27];
    float* outp = (float*)d_out;

    // Fixed region: folded bf16 weights + biases
    float* ws = (float*)d_ws;
    short* wTa1 = (short*)ws;
    short* wTa2 = wTa1 + WSH_A1;
    short* wTp1 = wTa2 + WSH_A2;
    short* wTp2 = wTp1 + WSH_A1;
    float* bfa1 = ws + WSH_TOT / 2;
    float* bfa2 = bfa1 + 128;
    float* bfp1 = bfa2 + 128;
    float* bfp2 = bfp1 + 128;
    float* dyn  = bfp2 + 128;
    const size_t fixed_floats = WSH_TOT / 2 + 512;

    int GB = 32;
    while (GB > 1) {
        size_t need = ((size_t)GB * EL_PER_BATCH + fixed_floats + 256) * sizeof(float);
        if (need <= ws_size) break;
        GB >>= 1;
    }
    const int ngroups = NB / GB;

    // dynamic regions with overlays
    float* heat = dyn;                                 // GB*EL_HEAT
    float* m    = heat + (size_t)GB * EL_HEAT;         // 64
    float* regB = m + 64;                              // GB*EL_OUT1
    float* regC = regB + (size_t)GB * EL_OUT1;         // GB*EL_OUT2
    float* regD = regC + (size_t)GB * EL_OUT2;         // GB*EL_MAP3
    float* regE = regD + (size_t)GB * EL_MAP3;         // GB*EL_FXBF
    float* pmm  = regE + (size_t)GB * EL_FXBF;         // 128
    float* px   = pmm + 128;                           // GB*EL_PX

    float* G    = regD;            // [lb][181][330] (dead after rowcombine)
    float* out1 = regB;            // ch-first f32
    float* out2 = regC;            // ch-last f32
    float* fbuf = regD;            // ch-last f32 (a1 out)
    short* fxbf = (short*)regE;    // ch-first bf16 [c][KPAD]
    float* pp1  = regB;            // ch-last f32 (out1 dead)
    float* pp2  = regD;            // ch-first f32 (fbuf dead)
    short* pmbf = (short*)regB;    // ch-first bf16 [p][KPAD] (pp1 dead)

    // fold weights
    wfold_k<<<(9 * 128 * CH2 + 255) / 256, 256, 0, stream>>>(a1_w, abn1_g, a1_b, abn1_b, wTa1, bfa1, CH2);
    wfold_k<<<(9 * 128 * CH3 + 255) / 256, 256, 0, stream>>>(a2_w, abn2_g, a2_b, abn2_b, wTa2, bfa2, CH3);
    wfold_k<<<(9 * 128 * CH2 + 255) / 256, 256, 0, stream>>>(p1_w, pbn1_g, p1_b, pbn1_b, wTp1, bfp1, CH2);
    wfold_k<<<(9 * 128 * CH3 + 255) / 256, 256, 0, stream>>>(p2_w, pbn2_g, p2_b, pbn2_b, wTp2, bfp2, CH3);

    const int ptiles = (PIX2 + 255) / 256;        // 15
    const int hblocks = (EL_HEAT + 255) / 256;    // 233

    for (int gidx = 0; gidx < ngroups; ++gidx) {
        const int b0 = gidx * GB;
        mm_init<<<1, 256, 0, stream>>>((unsigned*)m, (unsigned*)pmm);
        // S1: separable column scatter into G
        heat_scatter_cols<<<dim3(NSTRIP, GB), 256, 0, stream>>>(x_t, G, b0);
        // S2: row combine -> heat + fused max
        heat_rowcombine<<<dim3(hblocks, GB), 256, 0, stream>>>(G, heat, (unsigned*)m);
        conv1_pool<<<(GB * H1 * W1 + 255) / 256, 256, 0, stream>>>(
            heat, image, m, c1_w, c1_b, bn1_g, bn1_b, out1, b0, GB);
        conv2_pool<<<dim3(ptiles, CH2 / 8, GB), 256, 0, stream>>>(
            out1, c2_w, c2_b, bn2_g, bn2_b, out2);
        conv3x3_mfma<CH2, false, 0><<<dim3(6, H2, GB), 256, 0, stream>>>(out2, wTa1, bfa1, fbuf);
        conv3x3_mfma<CH3, true,  2><<<dim3(6, H2, GB), 256, 0, stream>>>(fbuf, wTa2, bfa2, fxbf);
        conv3x3_mfma<CH2, false, 0><<<dim3(6, H2, GB), 256, 0, stream>>>(out2, wTp1, bfp1, pp1);
        conv3x3_mfma<CH3, false, 1><<<dim3(6, H2, GB), 256, 0, stream>>>(pp1, wTp2, bfp2, pp2);
        pminmax<<<dim3(32, GB), 256, 0, stream>>>(pp2, (unsigned*)pmm);
        pmap_bf<<<dim3(ptiles, 128, GB), 256, 0, stream>>>(pp2, pmm, pmbf);
        einsum_mfma<<<dim3(8, GB), 256, 0, stream>>>(pmbf, fxbf, px);
        fc_k<<<GB * 64, 256, 0, stream>>>(px, fc_w, fc_b, outp, b0);
    }
}

// Round 11
// 1142.549 us; speedup vs baseline: 1.7932x; 1.5094x over previous
//
#include <hip/hip_runtime.h>
#include <hip/hip_bf16.h>

// Problem constants
#define NB 32
#define NT 1024
#define IH 180
#define IW 330
#define KSZ 37
#define XBINS 181
#define H1 90
#define W1 165
#define H2 45
#define W2 82
#define PIX2 (H2*W2)          // 3690
#define KTOT PIX2
#define KPAD 3712
#define CH1 32
#define CH2 64
#define CH3 128
#define NSTRIP 6

// Per-batch f32-slot counts
#define EL_HEAT (IH*IW)           // 59,400
#define EL_REGB (CH1*H1*W1)       // 475,200 : out1 f32 ch-first -> pp1 bf16 ch-last (236,160 slots)
#define EL_REGC (CH2*PIX2/2)      // 118,080 : out2 bf16 ch-last
#define EL_REGD (CH3*KPAD/2)      // 237,568 : G f32 (59,730) -> fbuf bf16 -> pp2/pm bf16 [c][KPAD]
#define EL_REGE (CH3*KPAD/2)      // 237,568 : fx bf16 [c][KPAD]
#define EL_PX   (CH3*CH3)         // 16,384
#define EL_PER_BATCH (EL_HEAT + EL_REGB + EL_REGC + EL_REGD + EL_REGE + EL_PX) // 1,144,200

// folded-weight sizes (bf16 shorts): wT[tap][oc=128][ic]
#define WSH_A1 (9*128*64)
#define WSH_A2 (9*128*128)
#define WSH_TOT (2*WSH_A1 + 2*WSH_A2)

typedef __attribute__((ext_vector_type(8))) short short8;
typedef __attribute__((ext_vector_type(4))) float floatx4;

__device__ __forceinline__ short f2bf(float v) {
    __hip_bfloat16 h = __float2bfloat16(v);
    return *reinterpret_cast<short*>(&h);
}
__device__ __forceinline__ float b2f(short s) {
    __hip_bfloat16 h = *reinterpret_cast<__hip_bfloat16*>(&s);
    return __bfloat162float(h);
}

// ---------------------------------------------------------------------------
__global__ __launch_bounds__(256) void mm_init(unsigned* __restrict__ m_bits,
                                               unsigned* __restrict__ pmm_bits) {
    int i = threadIdx.x;
    if (i < 64) {
        m_bits[i] = 0u;
        pmm_bits[2 * i]     = 0x7F800000u;   // +inf
        pmm_bits[2 * i + 1] = 0u;
    }
}

// ---------------------------------------------------------------------------
// S1: separable scatter — column profiles into G[xp][Y]. One LDS-atomic
// wave-instruction per point.
// ---------------------------------------------------------------------------
__global__ __launch_bounds__(256) void heat_scatter_cols(const float* __restrict__ x_t,
                                                         float* __restrict__ G,
                                                         int b0) {
    const int strip = blockIdx.x;
    const int lb = blockIdx.y;
    const int b = b0 + lb;
    const int c0 = strip * 64;
    const int cw = min(64, IW - c0);
    __shared__ float g[XBINS * 64];
    __shared__ float k1n[64];
    __shared__ float2 pts[NT];
    const int tid = threadIdx.x;

    if (tid < 64) {
        float v = 0.0f;
        if (tid < KSZ) {
            float ax = (float)tid - 18.0f;
            v = expf(-ax * ax / 18.0f);
        }
        k1n[tid] = v;
    }
    for (int i = tid; i < XBINS * 64; i += 256) g[i] = 0.0f;
    {
        const float2* xb = (const float2*)x_t + (size_t)b * NT;
        for (int i = tid; i < NT; i += 256) pts[i] = xb[i];
    }
    __syncthreads();
    if (tid == 0) {
        float s = 0.0f;
        for (int i = 0; i < KSZ; i++) s += k1n[i];
        float inv = 1.0f / s;
        for (int i = 0; i < KSZ; i++) k1n[i] *= inv;
    }
    __syncthreads();

    const int wave = tid >> 6;
    const int lane = tid & 63;
    const float kc = k1n[lane];

    for (int p = wave; p < NT; p += 4) {
        float x = pts[p].x, y = pts[p].y;
        if (isnan(x) || isnan(y)) continue;
        int xp = IH - (int)((x - 30.0f) * 180.0f);
        xp = min(max(xp, 0), 180);
        int yp = (int)((y - 120.0f) * 165.0f);
        int ys = min(max(yp - 18, 0), IW - 36);
        int ye = min(max(yp + 18, 0), IW);
        int nc = ye - ys;
        int col = ys + lane;
        if (lane < nc && col >= c0 && col < c0 + cw)
            atomicAdd(&g[xp * 64 + col - c0], kc);
    }
    __syncthreads();
    for (int i = tid; i < XBINS * cw; i += 256) {
        int row = i / cw, col = i % cw;
        G[((size_t)lb * XBINS + row) * IW + c0 + col] = g[row * 64 + col];
    }
}

// ---------------------------------------------------------------------------
// S2: row-combine + fused per-batch max
// ---------------------------------------------------------------------------
__global__ __launch_bounds__(256) void heat_rowcombine(const float* __restrict__ G,
                                                       float* __restrict__ heat,
                                                       unsigned* __restrict__ m_bits) {
    const int lb = blockIdx.y;
    const int tid = threadIdx.x;
    __shared__ float k1n[64];
    if (tid < 64) {
        float v = 0.0f;
        if (tid < KSZ) {
            float ax = (float)tid - 18.0f;
            v = expf(-ax * ax / 18.0f);
        }
        k1n[tid] = v;
    }
    __syncthreads();
    if (tid == 0) {
        float s = 0.0f;
        for (int i = 0; i < KSZ; i++) s += k1n[i];
        float inv = 1.0f / s;
        for (int i = 0; i < KSZ; i++) k1n[i] *= inv;
    }
    __syncthreads();

    const int idx = blockIdx.x * 256 + tid;
    float s = 0.0f;
    if (idx < EL_HEAT) {
        int X = idx / IW, Y = idx % IW;
        int lo = max(0, X - 17);
        int hi = (X >= IH - 36) ? 180 : X + 18;
        const float* Gb = G + (size_t)lb * XBINS * IW + Y;
        for (int xp = lo; xp <= hi; ++xp) {
            int xs = min(max(xp - 18, 0), IH - 36);
            s += k1n[X - xs] * Gb[(size_t)xp * IW];
        }
        heat[(size_t)lb * EL_HEAT + idx] = s;
    }
    __shared__ float red[256];
    red[tid] = s;
    __syncthreads();
    for (int st = 128; st > 0; st >>= 1) {
        if (tid < st) red[tid] = fmaxf(red[tid], red[tid + st]);
        __syncthreads();
    }
    if (tid == 0) atomicMax(&m_bits[lb], __float_as_uint(red[0]));
}

// ---------------------------------------------------------------------------
// K3: conv1(1->32) + BN + relu + pool (fuse folded); out1 f32 ch-first
// ---------------------------------------------------------------------------
__global__ __launch_bounds__(256) void conv1_pool(const float* __restrict__ heat,
                                                  const float* __restrict__ image,
                                                  const float* __restrict__ m,
                                                  const float* __restrict__ w,
                                                  const float* __restrict__ cb,
                                                  const float* __restrict__ g,
                                                  const float* __restrict__ bb,
                                                  float* __restrict__ out1,
                                                  int b0, int gb) {
    __shared__ float ws_[CH1 * 9];
    __shared__ float bs_[CH1];
    const int tid = threadIdx.x;
    for (int i = tid; i < CH1 * 9; i += 256) {
        int oc = i / 9;
        ws_[i] = w[i] * g[oc];
    }
    if (tid < CH1) bs_[tid] = cb[tid] * g[tid] + bb[tid];
    __syncthreads();

    int t = blockIdx.x * 256 + tid;
    if (t >= gb * H1 * W1) return;
    int lb = t / (H1 * W1);
    int r = t % (H1 * W1);
    int py = r / W1, px = r % W1;
    const float s = 0.7f / (m[lb] + 1e-10f);
    const float* hb = heat + (size_t)lb * EL_HEAT;
    const float* ib = image + (size_t)(b0 + lb) * EL_HEAT;

    float v[4][4];
    int y0 = 2 * py - 1, x0 = 2 * px - 1;
#pragma unroll
    for (int i = 0; i < 4; i++) {
#pragma unroll
        for (int j = 0; j < 4; j++) {
            int y = y0 + i, x = x0 + j;
            float val = 0.0f;
            if (y >= 0 && y < IH && x >= 0 && x < IW) {
                size_t idx = (size_t)y * IW + x;
                val = s * hb[idx] + 0.3f * ib[idx];
            }
            v[i][j] = val;
        }
    }
    for (int oc = 0; oc < CH1; oc++) {
        float a00 = 0, a01 = 0, a10 = 0, a11 = 0;
        const float* wp = &ws_[oc * 9];
#pragma unroll
        for (int ky = 0; ky < 3; ky++) {
#pragma unroll
            for (int kx = 0; kx < 3; kx++) {
                float wv = wp[ky * 3 + kx];
                a00 += wv * v[ky][kx];
                a01 += wv * v[ky][kx + 1];
                a10 += wv * v[ky + 1][kx];
                a11 += wv * v[ky + 1][kx + 1];
            }
        }
        float bias = bs_[oc];
        a00 = fmaxf(a00 + bias, 0.0f);
        a01 = fmaxf(a01 + bias, 0.0f);
        a10 = fmaxf(a10 + bias, 0.0f);
        a11 = fmaxf(a11 + bias, 0.0f);
        float mx = fmaxf(fmaxf(a00, a01), fmaxf(a10, a11));
        out1[(((size_t)lb * CH1 + oc) * H1 + py) * W1 + px] = mx;
    }
}

// ---------------------------------------------------------------------------
// K4: conv2(32->64) + BN + relu + pool. Output bf16 CHANNEL-LAST [pixel][oc]
// ---------------------------------------------------------------------------
__global__ __launch_bounds__(256) void conv2_pool(const float* __restrict__ in,
                                                  const float* __restrict__ w,
                                                  const float* __restrict__ cb,
                                                  const float* __restrict__ g,
                                                  const float* __restrict__ bb,
                                                  short* __restrict__ out) {
    __shared__ float ws_[8 * CH1 * 9];
    __shared__ float bs_[8];
    const int tid = threadIdx.x;
    const int ocg = blockIdx.y;
    const int lb = blockIdx.z;
    for (int i = tid; i < 8 * CH1 * 9; i += 256) {
        int o = i / (CH1 * 9);
        int rest = i % (CH1 * 9);
        int oc = ocg * 8 + o;
        ws_[i] = w[(size_t)oc * CH1 * 9 + rest] * g[oc];
    }
    if (tid < 8) {
        int oc = ocg * 8 + tid;
        bs_[tid] = cb[oc] * g[oc] + bb[oc];
    }
    __syncthreads();

    int pid = blockIdx.x * 256 + tid;
    if (pid >= PIX2) return;
    int py = pid / W2, px = pid % W2;
    float acc[8][4];
#pragma unroll
    for (int o = 0; o < 8; o++)
#pragma unroll
        for (int q = 0; q < 4; q++) acc[o][q] = 0.0f;

    int y0 = 2 * py - 1, x0 = 2 * px - 1;
    for (int ic = 0; ic < CH1; ic++) {
        float v[4][4];
        const float* ip = in + ((size_t)lb * CH1 + ic) * H1 * W1;
#pragma unroll
        for (int i = 0; i < 4; i++) {
#pragma unroll
            for (int j = 0; j < 4; j++) {
                int y = y0 + i, x = x0 + j;
                v[i][j] = (y >= 0 && y < H1 && x >= 0 && x < W1) ? ip[(size_t)y * W1 + x] : 0.0f;
            }
        }
#pragma unroll
        for (int o = 0; o < 8; o++) {
            const float* wp = &ws_[(o * CH1 + ic) * 9];
#pragma unroll
            for (int ky = 0; ky < 3; ky++) {
#pragma unroll
                for (int kx = 0; kx < 3; kx++) {
                    float wv = wp[ky * 3 + kx];
                    acc[o][0] += wv * v[ky][kx];
                    acc[o][1] += wv * v[ky][kx + 1];
                    acc[o][2] += wv * v[ky + 1][kx];
                    acc[o][3] += wv * v[ky + 1][kx + 1];
                }
            }
        }
    }
    short8 pk;
#pragma unroll
    for (int o = 0; o < 8; o++) {
        float bias = bs_[o];
        float a0 = fmaxf(acc[o][0] + bias, 0.0f);
        float a1 = fmaxf(acc[o][1] + bias, 0.0f);
        float a2 = fmaxf(acc[o][2] + bias, 0.0f);
        float a3 = fmaxf(acc[o][3] + bias, 0.0f);
        pk[o] = f2bf(fmaxf(fmaxf(a0, a1), fmaxf(a2, a3)));
    }
    *reinterpret_cast<short8*>(&out[((size_t)lb * PIX2 + pid) * CH2 + ocg * 8]) = pk;
}

// ---------------------------------------------------------------------------
// weight fold/transpose: wT[tap][oc][ic] = bf16(w[oc][ic][tap]*g[oc])
// ---------------------------------------------------------------------------
__global__ __launch_bounds__(256) void wfold_k(const float* __restrict__ w,
                                               const float* __restrict__ g,
                                               const float* __restrict__ cb,
                                               const float* __restrict__ bb,
                                               short* __restrict__ wT,
                                               float* __restrict__ bfold,
                                               int IC) {
    int i = blockIdx.x * 256 + threadIdx.x;
    int n = 9 * 128 * IC;
    if (i >= n) return;
    int tap = i / (128 * IC);
    int r = i % (128 * IC);
    int oc = r / IC;
    int ic = r % IC;
    wT[i] = f2bf(w[((size_t)oc * IC + ic) * 9 + tap] * g[oc]);
    if (tap == 0 && ic == 0) bfold[oc] = cb[oc] * g[oc] + bb[oc];
}

// ---------------------------------------------------------------------------
// K5-K8: 3x3 conv via bf16 MFMA; bf16 ch-last input; 32x4-pixel block tile
// (8 m-tiles x 2 n-acc per wave). OM: 0 = bf16 ch-last out, 2 = bf16
// ch-first [oc][KPAD] out.
// ---------------------------------------------------------------------------
template <int IC, bool SIG, int OM>
__global__ __launch_bounds__(256) void conv3x3_mfma(const short* __restrict__ in,
                                                    const short* __restrict__ wT,
                                                    const float* __restrict__ bfold,
                                                    short* __restrict__ outp) {
    const int xt = blockIdx.x;      // 0..2 (32 cols)
    const int yt = blockIdx.y;      // 0..11 (4 rows)
    const int lb = blockIdx.z;
    const int x0 = xt * 32, y0 = yt * 4;
    const int tid = threadIdx.x;
    const int wave = tid >> 6, lane = tid & 63;
    const int mm = lane & 15, q = lane >> 4;

    constexpr int KC = 32;
    constexpr int NCH = IC / KC;
    constexpr int AP = 40;
    __shared__ __align__(16) short tileA[6 * 34 * AP];   // 16,320 B

    floatx4 acc[16];
#pragma unroll
    for (int i = 0; i < 16; ++i) acc[i] = (floatx4){0.f, 0.f, 0.f, 0.f};

    const short* inb = in + (size_t)lb * PIX2 * IC;

    for (int c = 0; c < NCH; ++c) {
        const int ic0 = c * KC;
        for (int e = tid; e < 6 * 34 * (KC / 8); e += 256) {
            int dy = e / (34 * (KC / 8));
            int r  = e % (34 * (KC / 8));
            int tx = r / (KC / 8);
            int i8 = r % (KC / 8);
            int yin = y0 + dy - 1, xin = x0 + tx - 1;
            short8 hv = {0, 0, 0, 0, 0, 0, 0, 0};
            if (yin >= 0 && yin < H2 && xin >= 0 && xin < W2)
                hv = *reinterpret_cast<const short8*>(
                    &inb[((size_t)(yin * W2 + xin)) * IC + ic0 + i8 * 8]);
            *reinterpret_cast<short8*>(&tileA[(dy * 34 + tx) * AP + i8 * 8]) = hv;
        }
        __syncthreads();

        const int oc0 = wave * 32 + mm;
#pragma unroll
        for (int tap = 0; tap < 9; ++tap) {
            const int dy = tap / 3, dx = tap % 3;
            short8 b0 = *reinterpret_cast<const short8*>(
                &wT[((size_t)tap * 128 + oc0) * IC + ic0 + q * 8]);
            short8 b1 = *reinterpret_cast<const short8*>(
                &wT[((size_t)tap * 128 + oc0 + 16) * IC + ic0 + q * 8]);
#pragma unroll
            for (int t = 0; t < 8; ++t) {
                const int tr = t >> 1, tc = t & 1;
                short8 af = *reinterpret_cast<const short8*>(
                    &tileA[((tr + dy) * 34 + tc * 16 + dx + mm) * AP + q * 8]);
                acc[t * 2]     = __builtin_amdgcn_mfma_f32_16x16x32_bf16(af, b0, acc[t * 2], 0, 0, 0);
                acc[t * 2 + 1] = __builtin_amdgcn_mfma_f32_16x16x32_bf16(af, b1, acc[t * 2 + 1], 0, 0, 0);
            }
        }
        __syncthreads();
    }

    const int oc0 = wave * 32 + mm;
    const float bias0 = bfold[oc0];
    const float bias1 = bfold[oc0 + 16];
#pragma unroll
    for (int t = 0; t < 8; ++t) {
        const int tr = t >> 1, tc = t & 1;
        const int yy = y0 + tr;
        if (yy >= H2) continue;
#pragma unroll
        for (int r = 0; r < 4; ++r) {
            int x = x0 + tc * 16 + q * 4 + r;
            if (x >= W2) continue;
            float z0 = acc[t * 2][r] + bias0;
            float z1 = acc[t * 2 + 1][r] + bias1;
            if (SIG) {
                z0 = 1.0f / (1.0f + expf(-z0));
                z1 = 1.0f / (1.0f + expf(-z1));
            } else {
                z0 = fmaxf(z0, 0.0f);
                z1 = fmaxf(z1, 0.0f);
            }
            int hw = yy * W2 + x;
            if (OM == 0) {
                short* op = outp + ((size_t)lb * PIX2 + hw) * 128;
                op[oc0] = f2bf(z0);
                op[oc0 + 16] = f2bf(z1);
            } else {
                short* op = outp + (size_t)lb * 128 * KPAD;
                op[(size_t)oc0 * KPAD + hw] = f2bf(z0);
                op[(size_t)(oc0 + 16) * KPAD + hw] = f2bf(z1);
            }
        }
    }
}

// ---------------------------------------------------------------------------
// K9: per-batch min/max of pp2 (bf16 ch-first [c][KPAD], valid hw < PIX2)
// ---------------------------------------------------------------------------
__global__ __launch_bounds__(256) void pminmax(const short* __restrict__ p,
                                               unsigned* __restrict__ pmm_bits) {
    const int c = blockIdx.x;              // 0..127
    const int lb = blockIdx.y;
    const short* pb = p + (size_t)lb * 128 * KPAD + (size_t)c * KPAD;
    float mn = INFINITY, mx = 0.0f;
    for (int i = threadIdx.x; i < PIX2; i += 256) {
        float v = b2f(pb[i]);
        mn = fminf(mn, v);
        mx = fmaxf(mx, v);
    }
    __shared__ float rmn[256], rmx[256];
    rmn[threadIdx.x] = mn; rmx[threadIdx.x] = mx;
    __syncthreads();
    for (int s = 128; s > 0; s >>= 1) {
        if (threadIdx.x < s) {
            rmn[threadIdx.x] = fminf(rmn[threadIdx.x], rmn[threadIdx.x + s]);
            rmx[threadIdx.x] = fmaxf(rmx[threadIdx.x], rmx[threadIdx.x + s]);
        }
        __syncthreads();
    }
    if (threadIdx.x == 0) {
        atomicMin(&pmm_bits[lb * 2],     __float_as_uint(rmn[0]));
        atomicMax(&pmm_bits[lb * 2 + 1], __float_as_uint(rmx[0]));
    }
}

// ---------------------------------------------------------------------------
// K10: p_map in place on bf16 [c][KPAD]
// ---------------------------------------------------------------------------
__global__ __launch_bounds__(256) void pmap_bf(short* __restrict__ p,
                                               const float* __restrict__ mm_) {
    const int hwi = blockIdx.x * 256 + threadIdx.x;
    const int ch = blockIdx.y;
    const int lb = blockIdx.z;
    if (hwi >= PIX2) return;
    float mn = mm_[lb * 2], mx = mm_[lb * 2 + 1];
    float denom = fmaxf(mx - mn, 1e-4f);
    size_t idx = (size_t)lb * 128 * KPAD + (size_t)ch * KPAD + hwi;
    float v = (b2f(p[idx]) - mn) / denom;
    p[idx] = f2bf(1.0f / (1.0f + expf(-10.0f * (v - 0.5f))));
}

// ---------------------------------------------------------------------------
// K11: einsum via bf16 MFMA. A = pm[p][KPAD], B = fx[c][KPAD]; C[p][c].
// ---------------------------------------------------------------------------
__global__ __launch_bounds__(256) void einsum_mfma(const short* __restrict__ pm,
                                                   const short* __restrict__ fxb,
                                                   float* __restrict__ px) {
    const int ms = blockIdx.x;   // 0..7
    const int lb = blockIdx.y;
    const int tid = threadIdx.x;
    const int wave = tid >> 6, lane = tid & 63;
    const int mm = lane & 15, q = lane >> 4;
    constexpr int KC = 64;
    constexpr int AP = 72;
    __shared__ __align__(16) short As[16 * AP];
    __shared__ __align__(16) short Bs[128 * AP];
    floatx4 acc0 = {0.f, 0.f, 0.f, 0.f};
    floatx4 acc1 = {0.f, 0.f, 0.f, 0.f};
    const short* Ab = pm + (size_t)lb * 128 * KPAD + (size_t)ms * 16 * KPAD;
    const short* Bb = fxb + (size_t)lb * 128 * KPAD;
    const int nch = (KTOT + KC - 1) / KC;   // 58

    for (int c = 0; c < nch; ++c) {
        const int kk = c * KC;
        for (int e = tid; e < 1152; e += 256) {
            const short* src; short* dst; int i8;
            if (e < 128) { int row = e >> 3; i8 = e & 7; src = Ab + (size_t)row * KPAD; dst = &As[row * AP]; }
            else { int e2 = e - 128; int row = e2 >> 3; i8 = e2 & 7; src = Bb + (size_t)row * KPAD; dst = &Bs[row * AP]; }
            int k = kk + i8 * 8;
            short8 v;
            if (k + 8 <= KTOT) {
                v = *reinterpret_cast<const short8*>(src + k);
            } else {
#pragma unroll
                for (int j = 0; j < 8; ++j) v[j] = (k + j < KTOT) ? src[k + j] : (short)0;
            }
            *reinterpret_cast<short8*>(dst + i8 * 8) = v;
        }
        __syncthreads();
#pragma unroll
        for (int ks = 0; ks < 2; ++ks) {
            short8 af = *reinterpret_cast<const short8*>(&As[mm * AP + ks * 32 + q * 8]);
            short8 b0 = *reinterpret_cast<const short8*>(&Bs[(wave * 32 + mm) * AP + ks * 32 + q * 8]);
            short8 b1 = *reinterpret_cast<const short8*>(&Bs[(wave * 32 + 16 + mm) * AP + ks * 32 + q * 8]);
            acc0 = __builtin_amdgcn_mfma_f32_16x16x32_bf16(af, b0, acc0, 0, 0, 0);
            acc1 = __builtin_amdgcn_mfma_f32_16x16x32_bf16(af, b1, acc1, 0, 0, 0);
        }
        __syncthreads();
    }
    const float inv = 1.0f / (float)KTOT;
    float* pxb = px + (size_t)lb * EL_PX + (size_t)ms * 16 * 128;
    const int c0 = wave * 32 + mm;
#pragma unroll
    for (int r = 0; r < 4; ++r) {
        int p = q * 4 + r;
        pxb[p * 128 + c0] = acc0[r] * inv;
        pxb[p * 128 + c0 + 16] = acc1[r] * inv;
    }
}

// ---------------------------------------------------------------------------
// K12: FC -> f32 out
// ---------------------------------------------------------------------------
__global__ __launch_bounds__(256) void fc_k(const float* __restrict__ px,
                                            const float* __restrict__ w,
                                            const float* __restrict__ bias,
                                            float* __restrict__ out,
                                            int b0) {
    const int gw = blockIdx.x * 4 + (threadIdx.x >> 6);
    const int lane = threadIdx.x & 63;
    const int lb = gw >> 8;
    const int o = gw & 255;
    const float* xb = px + (size_t)lb * EL_PX;
    const float* wr = w + (size_t)o * EL_PX;
    float s = 0.0f;
    for (int k = lane; k < EL_PX; k += 64) s += xb[k] * wr[k];
#pragma unroll
    for (int off = 32; off > 0; off >>= 1) s += __shfl_down(s, off);
    if (lane == 0) out[(size_t)(b0 + lb) * 256 + o] = s + bias[o];
}

// ---------------------------------------------------------------------------
extern "C" void kernel_launch(void* const* d_in, const int* in_sizes, int n_in,
                              void* d_out, int out_size, void* d_ws, size_t ws_size,
                              hipStream_t stream) {
    const float* x_t   = (const float*)d_in[0];
    const float* image = (const float*)d_in[1];
    const float* c1_w  = (const float*)d_in[2];
    const float* c1_b  = (const float*)d_in[3];
    const float* bn1_g = (const float*)d_in[4];
    const float* bn1_b = (const float*)d_in[5];
    const float* c2_w  = (const float*)d_in[6];
    const float* c2_b  = (const float*)d_in[7];
    const float* bn2_g = (const float*)d_in[8];
    const float* bn2_b = (const float*)d_in[9];
    const float* a1_w  = (const float*)d_in[10];
    const float* a1_b  = (const float*)d_in[11];
    const float* abn1_g= (const float*)d_in[12];
    const float* abn1_b= (const float*)d_in[13];
    const float* a2_w  = (const float*)d_in[14];
    const float* a2_b  = (const float*)d_in[15];
    const float* abn2_g= (const float*)d_in[16];
    const float* abn2_b= (const float*)d_in[17];
    const float* p1_w  = (const float*)d_in[18];
    const float* p1_b  = (const float*)d_in[19];
    const float* pbn1_g= (const float*)d_in[20];
    const float* pbn1_b= (const float*)d_in[21];
    const float* p2_w  = (const float*)d_in[22];
    const float* p2_b  = (const float*)d_in[23];
    const float* pbn2_g= (const float*)d_in[24];
    const float* pbn2_b= (const float*)d_in[25];
    const float* fc_w  = (const float*)d_in[26];
    const float* fc_b  = (const float*)d_in[27];
    float* outp = (float*)d_out;

    // Fixed region: folded bf16 weights + biases
    float* ws = (float*)d_ws;
    short* wTa1 = (short*)ws;
    short* wTa2 = wTa1 + WSH_A1;
    short* wTp1 = wTa2 + WSH_A2;
    short* wTp2 = wTp1 + WSH_A1;
    float* bfa1 = ws + WSH_TOT / 2;
    float* bfa2 = bfa1 + 128;
    float* bfp1 = bfa2 + 128;
    float* bfp2 = bfp1 + 128;
    float* dyn  = bfp2 + 128;
    const size_t fixed_floats = WSH_TOT / 2 + 512;

    int GB = 32;
    while (GB > 1) {
        size_t need = ((size_t)GB * EL_PER_BATCH + fixed_floats + 256) * sizeof(float);
        if (need <= ws_size) break;
        GB >>= 1;
    }
    const int ngroups = NB / GB;

    float* heat = dyn;                                 // GB*EL_HEAT
    float* m    = heat + (size_t)GB * EL_HEAT;         // 64
    float* regB = m + 64;                              // GB*EL_REGB
    float* regC = regB + (size_t)GB * EL_REGB;         // GB*EL_REGC
    float* regD = regC + (size_t)GB * EL_REGC;         // GB*EL_REGD
    float* regE = regD + (size_t)GB * EL_REGD;         // GB*EL_REGE
    float* pmm  = regE + (size_t)GB * EL_REGE;         // 128
    float* px   = pmm + 128;                           // GB*EL_PX

    float* G     = regD;            // [lb][181][330] f32 (dead after rowcombine)
    float* out1  = regB;            // f32 ch-first
    short* out2b = (short*)regC;    // bf16 ch-last [pixel][64]
    short* fbuf  = (short*)regD;    // bf16 ch-last [pixel][128] (a1 out)
    short* fxbf  = (short*)regE;    // bf16 ch-first [c][KPAD]
    short* pp1   = (short*)regB;    // bf16 ch-last (out1 dead)
    short* pp2   = (short*)regD;    // bf16 ch-first [c][KPAD] (fbuf dead); pm in place

    wfold_k<<<(9 * 128 * CH2 + 255) / 256, 256, 0, stream>>>(a1_w, abn1_g, a1_b, abn1_b, wTa1, bfa1, CH2);
    wfold_k<<<(9 * 128 * CH3 + 255) / 256, 256, 0, stream>>>(a2_w, abn2_g, a2_b, abn2_b, wTa2, bfa2, CH3);
    wfold_k<<<(9 * 128 * CH2 + 255) / 256, 256, 0, stream>>>(p1_w, pbn1_g, p1_b, pbn1_b, wTp1, bfp1, CH2);
    wfold_k<<<(9 * 128 * CH3 + 255) / 256, 256, 0, stream>>>(p2_w, pbn2_g, p2_b, pbn2_b, wTp2, bfp2, CH3);

    const int ptiles = (PIX2 + 255) / 256;        // 15
    const int hblocks = (EL_HEAT + 255) / 256;    // 233

    for (int gidx = 0; gidx < ngroups; ++gidx) {
        const int b0 = gidx * GB;
        mm_init<<<1, 256, 0, stream>>>((unsigned*)m, (unsigned*)pmm);
        heat_scatter_cols<<<dim3(NSTRIP, GB), 256, 0, stream>>>(x_t, G, b0);
        heat_rowcombine<<<dim3(hblocks, GB), 256, 0, stream>>>(G, heat, (unsigned*)m);
        conv1_pool<<<(GB * H1 * W1 + 255) / 256, 256, 0, stream>>>(
            heat, image, m, c1_w, c1_b, bn1_g, bn1_b, out1, b0, GB);
        conv2_pool<<<dim3(ptiles, CH2 / 8, GB), 256, 0, stream>>>(
            out1, c2_w, c2_b, bn2_g, bn2_b, out2b);
        conv3x3_mfma<CH2, false, 0><<<dim3(3, 12, GB), 256, 0, stream>>>(out2b, wTa1, bfa1, fbuf);
        conv3x3_mfma<CH3, true,  2><<<dim3(3, 12, GB), 256, 0, stream>>>(fbuf, wTa2, bfa2, fxbf);
        conv3x3_mfma<CH2, false, 0><<<dim3(3, 12, GB), 256, 0, stream>>>(out2b, wTp1, bfp1, pp1);
        conv3x3_mfma<CH3, false, 2><<<dim3(3, 12, GB), 256, 0, stream>>>(pp1, wTp2, bfp2, pp2);
        pminmax<<<dim3(128, GB), 256, 0, stream>>>(pp2, (unsigned*)pmm);
        pmap_bf<<<dim3(ptiles, 128, GB), 256, 0, stream>>>(pp2, pmm);
        einsum_mfma<<<dim3(8, GB), 256, 0, stream>>>(pp2, fxbf, px);
        fc_k<<<GB * 64, 256, 0, stream>>>(px, fc_w, fc_b, outp, b0);
    }
}

// Round 12
// 910.027 us; speedup vs baseline: 2.2513x; 1.2555x over previous
//
#include <hip/hip_runtime.h>
#include <hip/hip_bf16.h>

// Problem constants
#define NB 32
#define NT 1024
#define IH 180
#define IW 330
#define KSZ 37
#define XBINS 181
#define H1 90
#define W1 165
#define H2 45
#define W2 82
#define PIX2 (H2*W2)          // 3690
#define KTOT PIX2
#define KPAD 3712
#define CH1 32
#define CH2 64
#define CH3 128
#define NSTRIP 6

// Per-batch f32-slot counts
#define EL_HEAT (IH*IW)           // 59,400
#define EL_REGB 237600            // out1 bf16 ch-last [H1*W1][32] (237,600) -> pp1 bf16 [PIX2][128] (236,160)
#define EL_REGC (CH2*PIX2/2)      // 118,080 : out2 bf16 ch-last [pixel][64]
#define EL_REGD (CH3*KPAD/2)      // 237,568 : G f32 -> fbuf bf16 -> pp2/pm bf16 [c][KPAD]
#define EL_REGE (CH3*KPAD/2)      // 237,568 : fx bf16 [c][KPAD]
#define EL_PX   (CH3*CH3)         // 16,384
#define EL_PER_BATCH (EL_HEAT + EL_REGB + EL_REGC + EL_REGD + EL_REGE + EL_PX) // 906,600

// folded-weight sizes (bf16 shorts)
#define WSH_A1 (9*128*64)
#define WSH_A2 (9*128*128)
#define WSH_C2 (9*64*32)
#define WSH_TOT (2*WSH_A1 + 2*WSH_A2 + WSH_C2)   // 460,800 shorts

typedef __attribute__((ext_vector_type(8))) short short8;
typedef __attribute__((ext_vector_type(4))) float floatx4;

__device__ __forceinline__ short f2bf(float v) {
    __hip_bfloat16 h = __float2bfloat16(v);
    return *reinterpret_cast<short*>(&h);
}
__device__ __forceinline__ float b2f(short s) {
    __hip_bfloat16 h = *reinterpret_cast<__hip_bfloat16*>(&s);
    return __bfloat162float(h);
}

// ---------------------------------------------------------------------------
__global__ __launch_bounds__(256) void mm_init(unsigned* __restrict__ m_bits,
                                               unsigned* __restrict__ pmm_bits) {
    int i = threadIdx.x;
    if (i < 64) {
        m_bits[i] = 0u;
        pmm_bits[2 * i]     = 0x7F800000u;   // +inf
        pmm_bits[2 * i + 1] = 0u;
    }
}

// ---------------------------------------------------------------------------
// S1: separable scatter — column profiles into G[xp][Y]
// ---------------------------------------------------------------------------
__global__ __launch_bounds__(256) void heat_scatter_cols(const float* __restrict__ x_t,
                                                         float* __restrict__ G,
                                                         int b0) {
    const int strip = blockIdx.x;
    const int lb = blockIdx.y;
    const int b = b0 + lb;
    const int c0 = strip * 64;
    const int cw = min(64, IW - c0);
    __shared__ float g[XBINS * 64];
    __shared__ float k1n[64];
    __shared__ float2 pts[NT];
    const int tid = threadIdx.x;

    if (tid < 64) {
        float v = 0.0f;
        if (tid < KSZ) {
            float ax = (float)tid - 18.0f;
            v = expf(-ax * ax / 18.0f);
        }
        k1n[tid] = v;
    }
    for (int i = tid; i < XBINS * 64; i += 256) g[i] = 0.0f;
    {
        const float2* xb = (const float2*)x_t + (size_t)b * NT;
        for (int i = tid; i < NT; i += 256) pts[i] = xb[i];
    }
    __syncthreads();
    if (tid == 0) {
        float s = 0.0f;
        for (int i = 0; i < KSZ; i++) s += k1n[i];
        float inv = 1.0f / s;
        for (int i = 0; i < KSZ; i++) k1n[i] *= inv;
    }
    __syncthreads();

    const int wave = tid >> 6;
    const int lane = tid & 63;
    const float kc = k1n[lane];

    for (int p = wave; p < NT; p += 4) {
        float x = pts[p].x, y = pts[p].y;
        if (isnan(x) || isnan(y)) continue;
        int xp = IH - (int)((x - 30.0f) * 180.0f);
        xp = min(max(xp, 0), 180);
        int yp = (int)((y - 120.0f) * 165.0f);
        int ys = min(max(yp - 18, 0), IW - 36);
        int ye = min(max(yp + 18, 0), IW);
        int nc = ye - ys;
        int col = ys + lane;
        if (lane < nc && col >= c0 && col < c0 + cw)
            atomicAdd(&g[xp * 64 + col - c0], kc);
    }
    __syncthreads();
    for (int i = tid; i < XBINS * cw; i += 256) {
        int row = i / cw, col = i % cw;
        G[((size_t)lb * XBINS + row) * IW + c0 + col] = g[row * 64 + col];
    }
}

// ---------------------------------------------------------------------------
// S2: row-combine + fused per-batch max
// ---------------------------------------------------------------------------
__global__ __launch_bounds__(256) void heat_rowcombine(const float* __restrict__ G,
                                                       float* __restrict__ heat,
                                                       unsigned* __restrict__ m_bits) {
    const int lb = blockIdx.y;
    const int tid = threadIdx.x;
    __shared__ float k1n[64];
    if (tid < 64) {
        float v = 0.0f;
        if (tid < KSZ) {
            float ax = (float)tid - 18.0f;
            v = expf(-ax * ax / 18.0f);
        }
        k1n[tid] = v;
    }
    __syncthreads();
    if (tid == 0) {
        float s = 0.0f;
        for (int i = 0; i < KSZ; i++) s += k1n[i];
        float inv = 1.0f / s;
        for (int i = 0; i < KSZ; i++) k1n[i] *= inv;
    }
    __syncthreads();

    const int idx = blockIdx.x * 256 + tid;
    float s = 0.0f;
    if (idx < EL_HEAT) {
        int X = idx / IW, Y = idx % IW;
        int lo = max(0, X - 17);
        int hi = (X >= IH - 36) ? 180 : X + 18;
        const float* Gb = G + (size_t)lb * XBINS * IW + Y;
        for (int xp = lo; xp <= hi; ++xp) {
            int xs = min(max(xp - 18, 0), IH - 36);
            s += k1n[X - xs] * Gb[(size_t)xp * IW];
        }
        heat[(size_t)lb * EL_HEAT + idx] = s;
    }
    __shared__ float red[256];
    red[tid] = s;
    __syncthreads();
    for (int st = 128; st > 0; st >>= 1) {
        if (tid < st) red[tid] = fmaxf(red[tid], red[tid + st]);
        __syncthreads();
    }
    if (tid == 0) atomicMax(&m_bits[lb], __float_as_uint(red[0]));
}

// ---------------------------------------------------------------------------
// K3: conv1(1->32) + BN + relu + pool (fuse folded); out bf16 ch-last [pix][32]
// ---------------------------------------------------------------------------
__global__ __launch_bounds__(256) void conv1_pool(const float* __restrict__ heat,
                                                  const float* __restrict__ image,
                                                  const float* __restrict__ m,
                                                  const float* __restrict__ w,
                                                  const float* __restrict__ cb,
                                                  const float* __restrict__ g,
                                                  const float* __restrict__ bb,
                                                  short* __restrict__ out1,
                                                  int b0, int gb) {
    __shared__ float ws_[CH1 * 9];
    __shared__ float bs_[CH1];
    const int tid = threadIdx.x;
    for (int i = tid; i < CH1 * 9; i += 256) {
        int oc = i / 9;
        ws_[i] = w[i] * g[oc];
    }
    if (tid < CH1) bs_[tid] = cb[tid] * g[tid] + bb[tid];
    __syncthreads();

    int t = blockIdx.x * 256 + tid;
    if (t >= gb * H1 * W1) return;
    int lb = t / (H1 * W1);
    int r = t % (H1 * W1);
    int py = r / W1, px = r % W1;
    const float s = 0.7f / (m[lb] + 1e-10f);
    const float* hb = heat + (size_t)lb * EL_HEAT;
    const float* ib = image + (size_t)(b0 + lb) * EL_HEAT;

    float v[4][4];
    int y0 = 2 * py - 1, x0 = 2 * px - 1;
#pragma unroll
    for (int i = 0; i < 4; i++) {
#pragma unroll
        for (int j = 0; j < 4; j++) {
            int y = y0 + i, x = x0 + j;
            float val = 0.0f;
            if (y >= 0 && y < IH && x >= 0 && x < IW) {
                size_t idx = (size_t)y * IW + x;
                val = s * hb[idx] + 0.3f * ib[idx];
            }
            v[i][j] = val;
        }
    }
    short8 pk[4];
#pragma unroll
    for (int oc = 0; oc < CH1; oc++) {
        float a00 = 0, a01 = 0, a10 = 0, a11 = 0;
        const float* wp = &ws_[oc * 9];
#pragma unroll
        for (int ky = 0; ky < 3; ky++) {
#pragma unroll
            for (int kx = 0; kx < 3; kx++) {
                float wv = wp[ky * 3 + kx];
                a00 += wv * v[ky][kx];
                a01 += wv * v[ky][kx + 1];
                a10 += wv * v[ky + 1][kx];
                a11 += wv * v[ky + 1][kx + 1];
            }
        }
        float bias = bs_[oc];
        a00 = fmaxf(a00 + bias, 0.0f);
        a01 = fmaxf(a01 + bias, 0.0f);
        a10 = fmaxf(a10 + bias, 0.0f);
        a11 = fmaxf(a11 + bias, 0.0f);
        pk[oc >> 3][oc & 7] = f2bf(fmaxf(fmaxf(a00, a01), fmaxf(a10, a11)));
    }
    short8* op = reinterpret_cast<short8*>(&out1[((size_t)lb * H1 * W1 + r) * CH1]);
#pragma unroll
    for (int vv = 0; vv < 4; vv++) op[vv] = pk[vv];
}

// ---------------------------------------------------------------------------
// weight fold/transpose: wT[tap][oc][ic] = bf16(w[oc][ic][tap]*g[oc])
// ---------------------------------------------------------------------------
__global__ __launch_bounds__(256) void wfold_k(const float* __restrict__ w,
                                               const float* __restrict__ g,
                                               const float* __restrict__ cb,
                                               const float* __restrict__ bb,
                                               short* __restrict__ wT,
                                               float* __restrict__ bfold,
                                               int OC, int IC) {
    int i = blockIdx.x * 256 + threadIdx.x;
    int n = 9 * OC * IC;
    if (i >= n) return;
    int tap = i / (OC * IC);
    int r = i % (OC * IC);
    int oc = r / IC;
    int ic = r % IC;
    wT[i] = f2bf(w[((size_t)oc * IC + ic) * 9 + tap] * g[oc]);
    if (tap == 0 && ic == 0) bfold[oc] = cb[oc] * g[oc] + bb[oc];
}

// ---------------------------------------------------------------------------
// K4: conv2(32->64) + BN + relu + 2x2 pool via bf16 MFMA.
// Block: 32x8 pre-pool tile; wave w = row-pair w. Pool fused in epilogue.
// in: bf16 ch-last [H1*W1][32]; out: bf16 ch-last [PIX2][64].
// ---------------------------------------------------------------------------
__global__ __launch_bounds__(256) void conv2_mfma(const short* __restrict__ in,
                                                  const short* __restrict__ wT,
                                                  const float* __restrict__ bfold,
                                                  short* __restrict__ out) {
    const int xt = blockIdx.x;   // 0..5 : 32 pre-pool cols
    const int yt = blockIdx.y;   // 0..11: 8 pre-pool rows
    const int lb = blockIdx.z;
    const int x0 = xt * 32, y0 = yt * 8;
    const int tid = threadIdx.x;
    const int wave = tid >> 6, lane = tid & 63;
    const int mm = lane & 15, q = lane >> 4;
    constexpr int AP = 40;
    __shared__ __align__(16) short tileA[10 * 34 * AP];   // 27,200 B

    floatx4 acc[2][2][4];
#pragma unroll
    for (int a = 0; a < 2; ++a)
#pragma unroll
        for (int bq = 0; bq < 2; ++bq)
#pragma unroll
            for (int j = 0; j < 4; ++j) acc[a][bq][j] = (floatx4){0.f, 0.f, 0.f, 0.f};

    const short* inb = in + (size_t)lb * (H1 * W1) * CH1;
    for (int e = tid; e < 10 * 34 * 4; e += 256) {
        int dy = e / (34 * 4);
        int r = e % (34 * 4);
        int tx = r / 4;
        int i8 = r % 4;
        int yin = y0 + dy - 1, xin = x0 + tx - 1;
        short8 hv = {0, 0, 0, 0, 0, 0, 0, 0};
        if (yin >= 0 && yin < H1 && xin >= 0 && xin < W1)
            hv = *reinterpret_cast<const short8*>(&inb[((size_t)(yin * W1 + xin)) * CH1 + i8 * 8]);
        *reinterpret_cast<short8*>(&tileA[(dy * 34 + tx) * AP + i8 * 8]) = hv;
    }
    __syncthreads();

#pragma unroll
    for (int tap = 0; tap < 9; ++tap) {
        const int dy = tap / 3, dx = tap % 3;
        short8 bf[4];
#pragma unroll
        for (int j = 0; j < 4; ++j)
            bf[j] = *reinterpret_cast<const short8*>(&wT[((size_t)tap * 64 + j * 16 + mm) * 32 + q * 8]);
#pragma unroll
        for (int row = 0; row < 2; ++row) {
#pragma unroll
            for (int xh = 0; xh < 2; ++xh) {
                short8 af = *reinterpret_cast<const short8*>(
                    &tileA[((2 * wave + row + dy) * 34 + xh * 16 + dx + mm) * AP + q * 8]);
#pragma unroll
                for (int j = 0; j < 4; ++j)
                    acc[row][xh][j] = __builtin_amdgcn_mfma_f32_16x16x32_bf16(af, bf[j], acc[row][xh][j], 0, 0, 0);
            }
        }
    }

    const int py = yt * 4 + wave;
    if (py < H2) {
        short* ob = out + (size_t)lb * PIX2 * CH2;
#pragma unroll
        for (int xh = 0; xh < 2; ++xh) {
#pragma unroll
            for (int j = 0; j < 4; ++j) {
                const float bias = bfold[j * 16 + mm];
#pragma unroll
                for (int rp = 0; rp < 2; ++rp) {
                    int px = xt * 16 + xh * 8 + q * 2 + rp;
                    if (px < W2) {
                        float v = fmaxf(fmaxf(acc[0][xh][j][2 * rp], acc[0][xh][j][2 * rp + 1]),
                                        fmaxf(acc[1][xh][j][2 * rp], acc[1][xh][j][2 * rp + 1]));
                        v = fmaxf(v + bias, 0.0f);
                        ob[((size_t)py * W2 + px) * CH2 + j * 16 + mm] = f2bf(v);
                    }
                }
            }
        }
    }
}

// ---------------------------------------------------------------------------
// K5-K8: 3x3 conv via bf16 MFMA; bf16 ch-last input; 32x4 tile.
// OM: 0 = bf16 ch-last out, 2 = bf16 ch-first [oc][KPAD] out.
// ---------------------------------------------------------------------------
template <int IC, bool SIG, int OM>
__global__ __launch_bounds__(256) void conv3x3_mfma(const short* __restrict__ in,
                                                    const short* __restrict__ wT,
                                                    const float* __restrict__ bfold,
                                                    short* __restrict__ outp) {
    const int xt = blockIdx.x;      // 0..2 (32 cols)
    const int yt = blockIdx.y;      // 0..11 (4 rows)
    const int lb = blockIdx.z;
    const int x0 = xt * 32, y0 = yt * 4;
    const int tid = threadIdx.x;
    const int wave = tid >> 6, lane = tid & 63;
    const int mm = lane & 15, q = lane >> 4;

    constexpr int KC = 32;
    constexpr int NCH = IC / KC;
    constexpr int AP = 40;
    __shared__ __align__(16) short tileA[6 * 34 * AP];   // 16,320 B

    floatx4 acc[16];
#pragma unroll
    for (int i = 0; i < 16; ++i) acc[i] = (floatx4){0.f, 0.f, 0.f, 0.f};

    const short* inb = in + (size_t)lb * PIX2 * IC;

    for (int c = 0; c < NCH; ++c) {
        const int ic0 = c * KC;
        for (int e = tid; e < 6 * 34 * (KC / 8); e += 256) {
            int dy = e / (34 * (KC / 8));
            int r  = e % (34 * (KC / 8));
            int tx = r / (KC / 8);
            int i8 = r % (KC / 8);
            int yin = y0 + dy - 1, xin = x0 + tx - 1;
            short8 hv = {0, 0, 0, 0, 0, 0, 0, 0};
            if (yin >= 0 && yin < H2 && xin >= 0 && xin < W2)
                hv = *reinterpret_cast<const short8*>(
                    &inb[((size_t)(yin * W2 + xin)) * IC + ic0 + i8 * 8]);
            *reinterpret_cast<short8*>(&tileA[(dy * 34 + tx) * AP + i8 * 8]) = hv;
        }
        __syncthreads();

        const int oc0 = wave * 32 + mm;
#pragma unroll
        for (int tap = 0; tap < 9; ++tap) {
            const int dy = tap / 3, dx = tap % 3;
            short8 b0 = *reinterpret_cast<const short8*>(
                &wT[((size_t)tap * 128 + oc0) * IC + ic0 + q * 8]);
            short8 b1 = *reinterpret_cast<const short8*>(
                &wT[((size_t)tap * 128 + oc0 + 16) * IC + ic0 + q * 8]);
#pragma unroll
            for (int t = 0; t < 8; ++t) {
                const int tr = t >> 1, tc = t & 1;
                short8 af = *reinterpret_cast<const short8*>(
                    &tileA[((tr + dy) * 34 + tc * 16 + dx + mm) * AP + q * 8]);
                acc[t * 2]     = __builtin_amdgcn_mfma_f32_16x16x32_bf16(af, b0, acc[t * 2], 0, 0, 0);
                acc[t * 2 + 1] = __builtin_amdgcn_mfma_f32_16x16x32_bf16(af, b1, acc[t * 2 + 1], 0, 0, 0);
            }
        }
        __syncthreads();
    }

    const int oc0 = wave * 32 + mm;
    const float bias0 = bfold[oc0];
    const float bias1 = bfold[oc0 + 16];
#pragma unroll
    for (int t = 0; t < 8; ++t) {
        const int tr = t >> 1, tc = t & 1;
        const int yy = y0 + tr;
        if (yy >= H2) continue;
#pragma unroll
        for (int r = 0; r < 4; ++r) {
            int x = x0 + tc * 16 + q * 4 + r;
            if (x >= W2) continue;
            float z0 = acc[t * 2][r] + bias0;
            float z1 = acc[t * 2 + 1][r] + bias1;
            if (SIG) {
                z0 = 1.0f / (1.0f + expf(-z0));
                z1 = 1.0f / (1.0f + expf(-z1));
            } else {
                z0 = fmaxf(z0, 0.0f);
                z1 = fmaxf(z1, 0.0f);
            }
            int hw = yy * W2 + x;
            if (OM == 0) {
                short* op = outp + ((size_t)lb * PIX2 + hw) * 128;
                op[oc0] = f2bf(z0);
                op[oc0 + 16] = f2bf(z1);
            } else {
                short* op = outp + (size_t)lb * 128 * KPAD;
                op[(size_t)oc0 * KPAD + hw] = f2bf(z0);
                op[(size_t)(oc0 + 16) * KPAD + hw] = f2bf(z1);
            }
        }
    }
}

// ---------------------------------------------------------------------------
// K9: per-batch min/max of pp2 (bf16 ch-first [c][KPAD], valid hw < PIX2)
// ---------------------------------------------------------------------------
__global__ __launch_bounds__(256) void pminmax(const short* __restrict__ p,
                                               unsigned* __restrict__ pmm_bits) {
    const int c = blockIdx.x;              // 0..127
    const int lb = blockIdx.y;
    const short* pb = p + (size_t)lb * 128 * KPAD + (size_t)c * KPAD;
    float mn = INFINITY, mx = 0.0f;
    for (int i = threadIdx.x; i < PIX2; i += 256) {
        float v = b2f(pb[i]);
        mn = fminf(mn, v);
        mx = fmaxf(mx, v);
    }
    __shared__ float rmn[256], rmx[256];
    rmn[threadIdx.x] = mn; rmx[threadIdx.x] = mx;
    __syncthreads();
    for (int s = 128; s > 0; s >>= 1) {
        if (threadIdx.x < s) {
            rmn[threadIdx.x] = fminf(rmn[threadIdx.x], rmn[threadIdx.x + s]);
            rmx[threadIdx.x] = fmaxf(rmx[threadIdx.x], rmx[threadIdx.x + s]);
        }
        __syncthreads();
    }
    if (threadIdx.x == 0) {
        atomicMin(&pmm_bits[lb * 2],     __float_as_uint(rmn[0]));
        atomicMax(&pmm_bits[lb * 2 + 1], __float_as_uint(rmx[0]));
    }
}

// ---------------------------------------------------------------------------
// K10: p_map in place on bf16 [c][KPAD]
// ---------------------------------------------------------------------------
__global__ __launch_bounds__(256) void pmap_bf(short* __restrict__ p,
                                               const float* __restrict__ mm_) {
    const int hwi = blockIdx.x * 256 + threadIdx.x;
    const int ch = blockIdx.y;
    const int lb = blockIdx.z;
    if (hwi >= PIX2) return;
    float mn = mm_[lb * 2], mx = mm_[lb * 2 + 1];
    float denom = fmaxf(mx - mn, 1e-4f);
    size_t idx = (size_t)lb * 128 * KPAD + (size_t)ch * KPAD + hwi;
    float v = (b2f(p[idx]) - mn) / denom;
    p[idx] = f2bf(1.0f / (1.0f + expf(-10.0f * (v - 0.5f))));
}

// ---------------------------------------------------------------------------
// K11: einsum via bf16 MFMA. A = pm[p][KPAD], B = fx[c][KPAD]; C[p][c].
// ---------------------------------------------------------------------------
__global__ __launch_bounds__(256) void einsum_mfma(const short* __restrict__ pm,
                                                   const short* __restrict__ fxb,
                                                   float* __restrict__ px) {
    const int ms = blockIdx.x;   // 0..7
    const int lb = blockIdx.y;
    const int tid = threadIdx.x;
    const int wave = tid >> 6, lane = tid & 63;
    const int mm = lane & 15, q = lane >> 4;
    constexpr int KC = 64;
    constexpr int AP = 72;
    __shared__ __align__(16) short As[16 * AP];
    __shared__ __align__(16) short Bs[128 * AP];
    floatx4 acc0 = {0.f, 0.f, 0.f, 0.f};
    floatx4 acc1 = {0.f, 0.f, 0.f, 0.f};
    const short* Ab = pm + (size_t)lb * 128 * KPAD + (size_t)ms * 16 * KPAD;
    const short* Bb = fxb + (size_t)lb * 128 * KPAD;
    const int nch = (KTOT + KC - 1) / KC;   // 58

    for (int c = 0; c < nch; ++c) {
        const int kk = c * KC;
        for (int e = tid; e < 1152; e += 256) {
            const short* src; short* dst; int i8;
            if (e < 128) { int row = e >> 3; i8 = e & 7; src = Ab + (size_t)row * KPAD; dst = &As[row * AP]; }
            else { int e2 = e - 128; int row = e2 >> 3; i8 = e2 & 7; src = Bb + (size_t)row * KPAD; dst = &Bs[row * AP]; }
            int k = kk + i8 * 8;
            short8 v;
            if (k + 8 <= KTOT) {
                v = *reinterpret_cast<const short8*>(src + k);
            } else {
#pragma unroll
                for (int j = 0; j < 8; ++j) v[j] = (k + j < KTOT) ? src[k + j] : (short)0;
            }
            *reinterpret_cast<short8*>(dst + i8 * 8) = v;
        }
        __syncthreads();
#pragma unroll
        for (int ks = 0; ks < 2; ++ks) {
            short8 af = *reinterpret_cast<const short8*>(&As[mm * AP + ks * 32 + q * 8]);
            short8 b0 = *reinterpret_cast<const short8*>(&Bs[(wave * 32 + mm) * AP + ks * 32 + q * 8]);
            short8 b1 = *reinterpret_cast<const short8*>(&Bs[(wave * 32 + 16 + mm) * AP + ks * 32 + q * 8]);
            acc0 = __builtin_amdgcn_mfma_f32_16x16x32_bf16(af, b0, acc0, 0, 0, 0);
            acc1 = __builtin_amdgcn_mfma_f32_16x16x32_bf16(af, b1, acc1, 0, 0, 0);
        }
        __syncthreads();
    }
    const float inv = 1.0f / (float)KTOT;
    float* pxb = px + (size_t)lb * EL_PX + (size_t)ms * 16 * 128;
    const int c0 = wave * 32 + mm;
#pragma unroll
    for (int r = 0; r < 4; ++r) {
        int p = q * 4 + r;
        pxb[p * 128 + c0] = acc0[r] * inv;
        pxb[p * 128 + c0 + 16] = acc1[r] * inv;
    }
}

// ---------------------------------------------------------------------------
// K12: FC -> f32 out
// ---------------------------------------------------------------------------
__global__ __launch_bounds__(256) void fc_k(const float* __restrict__ px,
                                            const float* __restrict__ w,
                                            const float* __restrict__ bias,
                                            float* __restrict__ out,
                                            int b0) {
    const int gw = blockIdx.x * 4 + (threadIdx.x >> 6);
    const int lane = threadIdx.x & 63;
    const int lb = gw >> 8;
    const int o = gw & 255;
    const float* xb = px + (size_t)lb * EL_PX;
    const float* wr = w + (size_t)o * EL_PX;
    float s = 0.0f;
    for (int k = lane; k < EL_PX; k += 64) s += xb[k] * wr[k];
#pragma unroll
    for (int off = 32; off > 0; off >>= 1) s += __shfl_down(s, off);
    if (lane == 0) out[(size_t)(b0 + lb) * 256 + o] = s + bias[o];
}

// ---------------------------------------------------------------------------
extern "C" void kernel_launch(void* const* d_in, const int* in_sizes, int n_in,
                              void* d_out, int out_size, void* d_ws, size_t ws_size,
                              hipStream_t stream) {
    const float* x_t   = (const float*)d_in[0];
    const float* image = (const float*)d_in[1];
    const float* c1_w  = (const float*)d_in[2];
    const float* c1_b  = (const float*)d_in[3];
    const float* bn1_g = (const float*)d_in[4];
    const float* bn1_b = (const float*)d_in[5];
    const float* c2_w  = (const float*)d_in[6];
    const float* c2_b  = (const float*)d_in[7];
    const float* bn2_g = (const float*)d_in[8];
    const float* bn2_b = (const float*)d_in[9];
    const float* a1_w  = (const float*)d_in[10];
    const float* a1_b  = (const float*)d_in[11];
    const float* abn1_g= (const float*)d_in[12];
    const float* abn1_b= (const float*)d_in[13];
    const float* a2_w  = (const float*)d_in[14];
    const float* a2_b  = (const float*)d_in[15];
    const float* abn2_g= (const float*)d_in[16];
    const float* abn2_b= (const float*)d_in[17];
    const float* p1_w  = (const float*)d_in[18];
    const float* p1_b  = (const float*)d_in[19];
    const float* pbn1_g= (const float*)d_in[20];
    const float* pbn1_b= (const float*)d_in[21];
    const float* p2_w  = (const float*)d_in[22];
    const float* p2_b  = (const float*)d_in[23];
    const float* pbn2_g= (const float*)d_in[24];
    const float* pbn2_b= (const float*)d_in[25];
    const float* fc_w  = (const float*)d_in[26];
    const float* fc_b  = (const float*)d_in[27];
    float* outp = (float*)d_out;

    // Fixed region: folded bf16 weights + biases
    float* ws = (float*)d_ws;
    short* wTa1 = (short*)ws;
    short* wTa2 = wTa1 + WSH_A1;
    short* wTp1 = wTa2 + WSH_A2;
    short* wTp2 = wTp1 + WSH_A1;
    short* wTc2 = wTp2 + WSH_A2;
    float* bfa1 = ws + WSH_TOT / 2;
    float* bfa2 = bfa1 + 128;
    float* bfp1 = bfa2 + 128;
    float* bfp2 = bfp1 + 128;
    float* bfc2 = bfp2 + 128;
    float* dyn  = bfc2 + 128;
    const size_t fixed_floats = WSH_TOT / 2 + 1024;

    int GB = 32;
    while (GB > 1) {
        size_t need = ((size_t)GB * EL_PER_BATCH + fixed_floats + 256) * sizeof(float);
        if (need <= ws_size) break;
        GB >>= 1;
    }
    const int ngroups = NB / GB;

    float* heat = dyn;                                 // GB*EL_HEAT
    float* m    = heat + (size_t)GB * EL_HEAT;         // 64
    float* regB = m + 64;                              // GB*EL_REGB
    float* regC = regB + (size_t)GB * EL_REGB;         // GB*EL_REGC
    float* regD = regC + (size_t)GB * EL_REGC;         // GB*EL_REGD
    float* regE = regD + (size_t)GB * EL_REGD;         // GB*EL_REGE
    float* pmm  = regE + (size_t)GB * EL_REGE;         // 128
    float* px   = pmm + 128;                           // GB*EL_PX

    float* G     = regD;            // [lb][181][330] f32 (dead after rowcombine)
    short* out1b = (short*)regB;    // bf16 ch-last [H1*W1][32]
    short* out2b = (short*)regC;    // bf16 ch-last [pixel][64]
    short* fbuf  = (short*)regD;    // bf16 ch-last [pixel][128] (a1 out)
    short* fxbf  = (short*)regE;    // bf16 ch-first [c][KPAD]
    short* pp1   = (short*)regB;    // bf16 ch-last (out1 dead)
    short* pp2   = (short*)regD;    // bf16 ch-first [c][KPAD] (fbuf dead); pm in place

    wfold_k<<<(9 * 128 * CH2 + 255) / 256, 256, 0, stream>>>(a1_w, abn1_g, a1_b, abn1_b, wTa1, bfa1, 128, CH2);
    wfold_k<<<(9 * 128 * CH3 + 255) / 256, 256, 0, stream>>>(a2_w, abn2_g, a2_b, abn2_b, wTa2, bfa2, 128, CH3);
    wfold_k<<<(9 * 128 * CH2 + 255) / 256, 256, 0, stream>>>(p1_w, pbn1_g, p1_b, pbn1_b, wTp1, bfp1, 128, CH2);
    wfold_k<<<(9 * 128 * CH3 + 255) / 256, 256, 0, stream>>>(p2_w, pbn2_g, p2_b, pbn2_b, wTp2, bfp2, 128, CH3);
    wfold_k<<<(9 * 64 * 32 + 255) / 256, 256, 0, stream>>>(c2_w, bn2_g, c2_b, bn2_b, wTc2, bfc2, 64, 32);

    const int ptiles = (PIX2 + 255) / 256;        // 15
    const int hblocks = (EL_HEAT + 255) / 256;    // 233

    for (int gidx = 0; gidx < ngroups; ++gidx) {
        const int b0 = gidx * GB;
        mm_init<<<1, 256, 0, stream>>>((unsigned*)m, (unsigned*)pmm);
        heat_scatter_cols<<<dim3(NSTRIP, GB), 256, 0, stream>>>(x_t, G, b0);
        heat_rowcombine<<<dim3(hblocks, GB), 256, 0, stream>>>(G, heat, (unsigned*)m);
        conv1_pool<<<(GB * H1 * W1 + 255) / 256, 256, 0, stream>>>(
            heat, image, m, c1_w, c1_b, bn1_g, bn1_b, out1b, b0, GB);
        conv2_mfma<<<dim3(6, 12, GB), 256, 0, stream>>>(out1b, wTc2, bfc2, out2b);
        conv3x3_mfma<CH2, false, 0><<<dim3(3, 12, GB), 256, 0, stream>>>(out2b, wTa1, bfa1, fbuf);
        conv3x3_mfma<CH3, true,  2><<<dim3(3, 12, GB), 256, 0, stream>>>(fbuf, wTa2, bfa2, fxbf);
        conv3x3_mfma<CH2, false, 0><<<dim3(3, 12, GB), 256, 0, stream>>>(out2b, wTp1, bfp1, pp1);
        conv3x3_mfma<CH3, false, 2><<<dim3(3, 12, GB), 256, 0, stream>>>(pp1, wTp2, bfp2, pp2);
        pminmax<<<dim3(128, GB), 256, 0, stream>>>(pp2, (unsigned*)pmm);
        pmap_bf<<<dim3(ptiles, 128, GB), 256, 0, stream>>>(pp2, pmm);
        einsum_mfma<<<dim3(8, GB), 256, 0, stream>>>(pp2, fxbf, px);
        fc_k<<<GB * 64, 256, 0, stream>>>(px, fc_w, fc_b, outp, b0);
    }
}

// Round 13
// 819.219 us; speedup vs baseline: 2.5009x; 1.1108x over previous
//
#include <hip/hip_runtime.h>
#include <hip/hip_bf16.h>

// Problem constants
#define NB 32
#define NT 1024
#define IH 180
#define IW 330
#define KSZ 37
#define XBINS 181
#define H1 90
#define W1 165
#define H2 45
#define W2 82
#define PIX2 (H2*W2)          // 3690
#define KTOT PIX2
#define KPAD 3712
#define CH1 32
#define CH2 64
#define CH3 128
#define NSTRIP 6
#define NKC 8                 // einsum K-chunks (512 each over KPAD)

// Per-batch f32-slot counts
#define EL_HEAT (IH*IW)           // 59,400
#define EL_REGB 237600            // out1 bf16 [H1*W1][32] -> pp1 bf16 [PIX2][128] -> px_part f32 (NKC*EL_PX=131,072)
#define EL_REGC (CH2*PIX2/2)      // 118,080 : out2 bf16 ch-last [pixel][64]
#define EL_REGD (CH3*KPAD/2)      // 237,568 : G f32 -> fbuf bf16 -> pp2 bf16 [c][KPAD]
#define EL_REGE (CH3*KPAD/2)      // 237,568 : fx bf16 [c][KPAD]
#define EL_PX   (CH3*CH3)         // 16,384
#define EL_PER_BATCH (EL_HEAT + EL_REGB + EL_REGC + EL_REGD + EL_REGE + EL_PX) // 906,600

// folded-weight sizes (bf16 shorts)
#define WSH_A1 (9*128*64)
#define WSH_A2 (9*128*128)
#define WSH_C2 (9*64*32)
#define WSH_TOT (2*WSH_A1 + 2*WSH_A2 + WSH_C2)   // 460,800 shorts

typedef __attribute__((ext_vector_type(8))) short short8;
typedef __attribute__((ext_vector_type(4))) float floatx4;

__device__ __forceinline__ short f2bf(float v) {
    __hip_bfloat16 h = __float2bfloat16(v);
    return *reinterpret_cast<short*>(&h);
}
__device__ __forceinline__ float b2f(short s) {
    __hip_bfloat16 h = *reinterpret_cast<__hip_bfloat16*>(&s);
    return __bfloat162float(h);
}

// ---------------------------------------------------------------------------
__global__ __launch_bounds__(256) void mm_init(unsigned* __restrict__ m_bits,
                                               unsigned* __restrict__ pmm_bits) {
    int i = threadIdx.x;
    if (i < 64) {
        m_bits[i] = 0u;
        pmm_bits[2 * i]     = 0x7F800000u;   // +inf
        pmm_bits[2 * i + 1] = 0u;
    }
}

// ---------------------------------------------------------------------------
// S1: separable scatter — column profiles into G[xp][Y]
// ---------------------------------------------------------------------------
__global__ __launch_bounds__(256) void heat_scatter_cols(const float* __restrict__ x_t,
                                                         float* __restrict__ G,
                                                         int b0) {
    const int strip = blockIdx.x;
    const int lb = blockIdx.y;
    const int b = b0 + lb;
    const int c0 = strip * 64;
    const int cw = min(64, IW - c0);
    __shared__ float g[XBINS * 64];
    __shared__ float k1n[64];
    __shared__ float2 pts[NT];
    const int tid = threadIdx.x;

    if (tid < 64) {
        float v = 0.0f;
        if (tid < KSZ) {
            float ax = (float)tid - 18.0f;
            v = expf(-ax * ax / 18.0f);
        }
        k1n[tid] = v;
    }
    for (int i = tid; i < XBINS * 64; i += 256) g[i] = 0.0f;
    {
        const float2* xb = (const float2*)x_t + (size_t)b * NT;
        for (int i = tid; i < NT; i += 256) pts[i] = xb[i];
    }
    __syncthreads();
    if (tid == 0) {
        float s = 0.0f;
        for (int i = 0; i < KSZ; i++) s += k1n[i];
        float inv = 1.0f / s;
        for (int i = 0; i < KSZ; i++) k1n[i] *= inv;
    }
    __syncthreads();

    const int wave = tid >> 6;
    const int lane = tid & 63;
    const float kc = k1n[lane];

    for (int p = wave; p < NT; p += 4) {
        float x = pts[p].x, y = pts[p].y;
        if (isnan(x) || isnan(y)) continue;
        int xp = IH - (int)((x - 30.0f) * 180.0f);
        xp = min(max(xp, 0), 180);
        int yp = (int)((y - 120.0f) * 165.0f);
        int ys = min(max(yp - 18, 0), IW - 36);
        int ye = min(max(yp + 18, 0), IW);
        int nc = ye - ys;
        int col = ys + lane;
        if (lane < nc && col >= c0 && col < c0 + cw)
            atomicAdd(&g[xp * 64 + col - c0], kc);
    }
    __syncthreads();
    for (int i = tid; i < XBINS * cw; i += 256) {
        int row = i / cw, col = i % cw;
        G[((size_t)lb * XBINS + row) * IW + c0 + col] = g[row * 64 + col];
    }
}

// ---------------------------------------------------------------------------
// S2: row-combine + fused per-batch max
// ---------------------------------------------------------------------------
__global__ __launch_bounds__(256) void heat_rowcombine(const float* __restrict__ G,
                                                       float* __restrict__ heat,
                                                       unsigned* __restrict__ m_bits) {
    const int lb = blockIdx.y;
    const int tid = threadIdx.x;
    __shared__ float k1n[64];
    if (tid < 64) {
        float v = 0.0f;
        if (tid < KSZ) {
            float ax = (float)tid - 18.0f;
            v = expf(-ax * ax / 18.0f);
        }
        k1n[tid] = v;
    }
    __syncthreads();
    if (tid == 0) {
        float s = 0.0f;
        for (int i = 0; i < KSZ; i++) s += k1n[i];
        float inv = 1.0f / s;
        for (int i = 0; i < KSZ; i++) k1n[i] *= inv;
    }
    __syncthreads();

    const int idx = blockIdx.x * 256 + tid;
    float s = 0.0f;
    if (idx < EL_HEAT) {
        int X = idx / IW, Y = idx % IW;
        int lo = max(0, X - 17);
        int hi = (X >= IH - 36) ? 180 : X + 18;
        const float* Gb = G + (size_t)lb * XBINS * IW + Y;
        for (int xp = lo; xp <= hi; ++xp) {
            int xs = min(max(xp - 18, 0), IH - 36);
            s += k1n[X - xs] * Gb[(size_t)xp * IW];
        }
        heat[(size_t)lb * EL_HEAT + idx] = s;
    }
    __shared__ float red[256];
    red[tid] = s;
    __syncthreads();
    for (int st = 128; st > 0; st >>= 1) {
        if (tid < st) red[tid] = fmaxf(red[tid], red[tid + st]);
        __syncthreads();
    }
    if (tid == 0) atomicMax(&m_bits[lb], __float_as_uint(red[0]));
}

// ---------------------------------------------------------------------------
// K3: conv1(1->32) + BN + relu + pool (fuse folded); out bf16 ch-last [pix][32]
// ---------------------------------------------------------------------------
__global__ __launch_bounds__(256) void conv1_pool(const float* __restrict__ heat,
                                                  const float* __restrict__ image,
                                                  const float* __restrict__ m,
                                                  const float* __restrict__ w,
                                                  const float* __restrict__ cb,
                                                  const float* __restrict__ g,
                                                  const float* __restrict__ bb,
                                                  short* __restrict__ out1,
                                                  int b0, int gb) {
    __shared__ float ws_[CH1 * 9];
    __shared__ float bs_[CH1];
    const int tid = threadIdx.x;
    for (int i = tid; i < CH1 * 9; i += 256) {
        int oc = i / 9;
        ws_[i] = w[i] * g[oc];
    }
    if (tid < CH1) bs_[tid] = cb[tid] * g[tid] + bb[tid];
    __syncthreads();

    int t = blockIdx.x * 256 + tid;
    if (t >= gb * H1 * W1) return;
    int lb = t / (H1 * W1);
    int r = t % (H1 * W1);
    int py = r / W1, px = r % W1;
    const float s = 0.7f / (m[lb] + 1e-10f);
    const float* hb = heat + (size_t)lb * EL_HEAT;
    const float* ib = image + (size_t)(b0 + lb) * EL_HEAT;

    float v[4][4];
    int y0 = 2 * py - 1, x0 = 2 * px - 1;
#pragma unroll
    for (int i = 0; i < 4; i++) {
#pragma unroll
        for (int j = 0; j < 4; j++) {
            int y = y0 + i, x = x0 + j;
            float val = 0.0f;
            if (y >= 0 && y < IH && x >= 0 && x < IW) {
                size_t idx = (size_t)y * IW + x;
                val = s * hb[idx] + 0.3f * ib[idx];
            }
            v[i][j] = val;
        }
    }
    short8 pk[4];
#pragma unroll
    for (int oc = 0; oc < CH1; oc++) {
        float a00 = 0, a01 = 0, a10 = 0, a11 = 0;
        const float* wp = &ws_[oc * 9];
#pragma unroll
        for (int ky = 0; ky < 3; ky++) {
#pragma unroll
            for (int kx = 0; kx < 3; kx++) {
                float wv = wp[ky * 3 + kx];
                a00 += wv * v[ky][kx];
                a01 += wv * v[ky][kx + 1];
                a10 += wv * v[ky + 1][kx];
                a11 += wv * v[ky + 1][kx + 1];
            }
        }
        float bias = bs_[oc];
        a00 = fmaxf(a00 + bias, 0.0f);
        a01 = fmaxf(a01 + bias, 0.0f);
        a10 = fmaxf(a10 + bias, 0.0f);
        a11 = fmaxf(a11 + bias, 0.0f);
        pk[oc >> 3][oc & 7] = f2bf(fmaxf(fmaxf(a00, a01), fmaxf(a10, a11)));
    }
    short8* op = reinterpret_cast<short8*>(&out1[((size_t)lb * H1 * W1 + r) * CH1]);
#pragma unroll
    for (int vv = 0; vv < 4; vv++) op[vv] = pk[vv];
}

// ---------------------------------------------------------------------------
// weight fold/transpose: wT[tap][oc][ic] = bf16(w[oc][ic][tap]*g[oc])
// ---------------------------------------------------------------------------
__global__ __launch_bounds__(256) void wfold_k(const float* __restrict__ w,
                                               const float* __restrict__ g,
                                               const float* __restrict__ cb,
                                               const float* __restrict__ bb,
                                               short* __restrict__ wT,
                                               float* __restrict__ bfold,
                                               int OC, int IC) {
    int i = blockIdx.x * 256 + threadIdx.x;
    int n = 9 * OC * IC;
    if (i >= n) return;
    int tap = i / (OC * IC);
    int r = i % (OC * IC);
    int oc = r / IC;
    int ic = r % IC;
    wT[i] = f2bf(w[((size_t)oc * IC + ic) * 9 + tap] * g[oc]);
    if (tap == 0 && ic == 0) bfold[oc] = cb[oc] * g[oc] + bb[oc];
}

// ---------------------------------------------------------------------------
// K4: conv2(32->64) + BN + relu + 2x2 pool via bf16 MFMA.
// ---------------------------------------------------------------------------
__global__ __launch_bounds__(256) void conv2_mfma(const short* __restrict__ in,
                                                  const short* __restrict__ wT,
                                                  const float* __restrict__ bfold,
                                                  short* __restrict__ out) {
    const int xt = blockIdx.x;   // 0..5 : 32 pre-pool cols
    const int yt = blockIdx.y;   // 0..11: 8 pre-pool rows
    const int lb = blockIdx.z;
    const int x0 = xt * 32, y0 = yt * 8;
    const int tid = threadIdx.x;
    const int wave = tid >> 6, lane = tid & 63;
    const int mm = lane & 15, q = lane >> 4;
    constexpr int AP = 40;
    __shared__ __align__(16) short tileA[10 * 34 * AP];

    floatx4 acc[2][2][4];
#pragma unroll
    for (int a = 0; a < 2; ++a)
#pragma unroll
        for (int bq = 0; bq < 2; ++bq)
#pragma unroll
            for (int j = 0; j < 4; ++j) acc[a][bq][j] = (floatx4){0.f, 0.f, 0.f, 0.f};

    const short* inb = in + (size_t)lb * (H1 * W1) * CH1;
    for (int e = tid; e < 10 * 34 * 4; e += 256) {
        int dy = e / (34 * 4);
        int r = e % (34 * 4);
        int tx = r / 4;
        int i8 = r % 4;
        int yin = y0 + dy - 1, xin = x0 + tx - 1;
        short8 hv = {0, 0, 0, 0, 0, 0, 0, 0};
        if (yin >= 0 && yin < H1 && xin >= 0 && xin < W1)
            hv = *reinterpret_cast<const short8*>(&inb[((size_t)(yin * W1 + xin)) * CH1 + i8 * 8]);
        *reinterpret_cast<short8*>(&tileA[(dy * 34 + tx) * AP + i8 * 8]) = hv;
    }
    __syncthreads();

#pragma unroll
    for (int tap = 0; tap < 9; ++tap) {
        const int dy = tap / 3, dx = tap % 3;
        short8 bf[4];
#pragma unroll
        for (int j = 0; j < 4; ++j)
            bf[j] = *reinterpret_cast<const short8*>(&wT[((size_t)tap * 64 + j * 16 + mm) * 32 + q * 8]);
#pragma unroll
        for (int row = 0; row < 2; ++row) {
#pragma unroll
            for (int xh = 0; xh < 2; ++xh) {
                short8 af = *reinterpret_cast<const short8*>(
                    &tileA[((2 * wave + row + dy) * 34 + xh * 16 + dx + mm) * AP + q * 8]);
#pragma unroll
                for (int j = 0; j < 4; ++j)
                    acc[row][xh][j] = __builtin_amdgcn_mfma_f32_16x16x32_bf16(af, bf[j], acc[row][xh][j], 0, 0, 0);
            }
        }
    }

    const int py = yt * 4 + wave;
    if (py < H2) {
        short* ob = out + (size_t)lb * PIX2 * CH2;
#pragma unroll
        for (int xh = 0; xh < 2; ++xh) {
#pragma unroll
            for (int j = 0; j < 4; ++j) {
                const float bias = bfold[j * 16 + mm];
#pragma unroll
                for (int rp = 0; rp < 2; ++rp) {
                    int px = xt * 16 + xh * 8 + q * 2 + rp;
                    if (px < W2) {
                        float v = fmaxf(fmaxf(acc[0][xh][j][2 * rp], acc[0][xh][j][2 * rp + 1]),
                                        fmaxf(acc[1][xh][j][2 * rp], acc[1][xh][j][2 * rp + 1]));
                        v = fmaxf(v + bias, 0.0f);
                        ob[((size_t)py * W2 + px) * CH2 + j * 16 + mm] = f2bf(v);
                    }
                }
            }
        }
    }
}

// ---------------------------------------------------------------------------
// K5-K8: 3x3 conv via bf16 MFMA; bf16 ch-last input; 32x4 tile.
// OM: 0 = bf16 ch-last out, 2 = bf16 ch-first [oc][KPAD] out.
// ---------------------------------------------------------------------------
template <int IC, bool SIG, int OM>
__global__ __launch_bounds__(256) void conv3x3_mfma(const short* __restrict__ in,
                                                    const short* __restrict__ wT,
                                                    const float* __restrict__ bfold,
                                                    short* __restrict__ outp) {
    const int xt = blockIdx.x;      // 0..2 (32 cols)
    const int yt = blockIdx.y;      // 0..11 (4 rows)
    const int lb = blockIdx.z;
    const int x0 = xt * 32, y0 = yt * 4;
    const int tid = threadIdx.x;
    const int wave = tid >> 6, lane = tid & 63;
    const int mm = lane & 15, q = lane >> 4;

    constexpr int KC = 32;
    constexpr int NCH = IC / KC;
    constexpr int AP = 40;
    __shared__ __align__(16) short tileA[6 * 34 * AP];

    floatx4 acc[16];
#pragma unroll
    for (int i = 0; i < 16; ++i) acc[i] = (floatx4){0.f, 0.f, 0.f, 0.f};

    const short* inb = in + (size_t)lb * PIX2 * IC;

    for (int c = 0; c < NCH; ++c) {
        const int ic0 = c * KC;
        for (int e = tid; e < 6 * 34 * (KC / 8); e += 256) {
            int dy = e / (34 * (KC / 8));
            int r  = e % (34 * (KC / 8));
            int tx = r / (KC / 8);
            int i8 = r % (KC / 8);
            int yin = y0 + dy - 1, xin = x0 + tx - 1;
            short8 hv = {0, 0, 0, 0, 0, 0, 0, 0};
            if (yin >= 0 && yin < H2 && xin >= 0 && xin < W2)
                hv = *reinterpret_cast<const short8*>(
                    &inb[((size_t)(yin * W2 + xin)) * IC + ic0 + i8 * 8]);
            *reinterpret_cast<short8*>(&tileA[(dy * 34 + tx) * AP + i8 * 8]) = hv;
        }
        __syncthreads();

        const int oc0 = wave * 32 + mm;
#pragma unroll
        for (int tap = 0; tap < 9; ++tap) {
            const int dy = tap / 3, dx = tap % 3;
            short8 b0 = *reinterpret_cast<const short8*>(
                &wT[((size_t)tap * 128 + oc0) * IC + ic0 + q * 8]);
            short8 b1 = *reinterpret_cast<const short8*>(
                &wT[((size_t)tap * 128 + oc0 + 16) * IC + ic0 + q * 8]);
#pragma unroll
            for (int t = 0; t < 8; ++t) {
                const int tr = t >> 1, tc = t & 1;
                short8 af = *reinterpret_cast<const short8*>(
                    &tileA[((tr + dy) * 34 + tc * 16 + dx + mm) * AP + q * 8]);
                acc[t * 2]     = __builtin_amdgcn_mfma_f32_16x16x32_bf16(af, b0, acc[t * 2], 0, 0, 0);
                acc[t * 2 + 1] = __builtin_amdgcn_mfma_f32_16x16x32_bf16(af, b1, acc[t * 2 + 1], 0, 0, 0);
            }
        }
        __syncthreads();
    }

    const int oc0 = wave * 32 + mm;
    const float bias0 = bfold[oc0];
    const float bias1 = bfold[oc0 + 16];
#pragma unroll
    for (int t = 0; t < 8; ++t) {
        const int tr = t >> 1, tc = t & 1;
        const int yy = y0 + tr;
        if (yy >= H2) continue;
#pragma unroll
        for (int r = 0; r < 4; ++r) {
            int x = x0 + tc * 16 + q * 4 + r;
            if (x >= W2) continue;
            float z0 = acc[t * 2][r] + bias0;
            float z1 = acc[t * 2 + 1][r] + bias1;
            if (SIG) {
                z0 = 1.0f / (1.0f + expf(-z0));
                z1 = 1.0f / (1.0f + expf(-z1));
            } else {
                z0 = fmaxf(z0, 0.0f);
                z1 = fmaxf(z1, 0.0f);
            }
            int hw = yy * W2 + x;
            if (OM == 0) {
                short* op = outp + ((size_t)lb * PIX2 + hw) * 128;
                op[oc0] = f2bf(z0);
                op[oc0 + 16] = f2bf(z1);
            } else {
                short* op = outp + (size_t)lb * 128 * KPAD;
                op[(size_t)oc0 * KPAD + hw] = f2bf(z0);
                op[(size_t)(oc0 + 16) * KPAD + hw] = f2bf(z1);
            }
        }
    }
}

// ---------------------------------------------------------------------------
// K9: per-batch min/max of pp2 (bf16 ch-first [c][KPAD], valid hw < PIX2)
// ---------------------------------------------------------------------------
__global__ __launch_bounds__(256) void pminmax(const short* __restrict__ p,
                                               unsigned* __restrict__ pmm_bits) {
    const int c = blockIdx.x;              // 0..127
    const int lb = blockIdx.y;
    const short* pb = p + (size_t)lb * 128 * KPAD + (size_t)c * KPAD;
    float mn = INFINITY, mx = 0.0f;
    for (int i = threadIdx.x; i < PIX2; i += 256) {
        float v = b2f(pb[i]);
        mn = fminf(mn, v);
        mx = fmaxf(mx, v);
    }
    __shared__ float rmn[256], rmx[256];
    rmn[threadIdx.x] = mn; rmx[threadIdx.x] = mx;
    __syncthreads();
    for (int s = 128; s > 0; s >>= 1) {
        if (threadIdx.x < s) {
            rmn[threadIdx.x] = fminf(rmn[threadIdx.x], rmn[threadIdx.x + s]);
            rmx[threadIdx.x] = fmaxf(rmx[threadIdx.x], rmx[threadIdx.x + s]);
        }
        __syncthreads();
    }
    if (threadIdx.x == 0) {
        atomicMin(&pmm_bits[lb * 2],     __float_as_uint(rmn[0]));
        atomicMax(&pmm_bits[lb * 2 + 1], __float_as_uint(rmx[0]));
    }
}

// ---------------------------------------------------------------------------
// K11a: K-split einsum via bf16 MFMA, pmap fused into A-staging.
// Grid (NKC kchunks of 512, GB). Block computes full 128x128 C-partial.
// A = sigmoid(10*((pp2-mn)/denom - 0.5)) staged on the fly; B = fx.
// Wave w owns m-tiles {2w, 2w+1} x all 8 n-tiles (64 f32 accs).
// px_part[(kc*gb+lb)][p][c]
// ---------------------------------------------------------------------------
__global__ __launch_bounds__(256) void einsum_part(const short* __restrict__ pp2,
                                                   const short* __restrict__ fxb,
                                                   const float* __restrict__ mm_,
                                                   float* __restrict__ px_part) {
    const int kc = blockIdx.x;   // 0..NKC-1
    const int lb = blockIdx.y;
    const int gb = gridDim.y;
    const int tid = threadIdx.x;
    const int wave = tid >> 6, lane = tid & 63;
    const int mm = lane & 15, q = lane >> 4;
    constexpr int AP = 72;
    __shared__ __align__(16) short As[128 * AP];
    __shared__ __align__(16) short Bs[128 * AP];

    const float mn = mm_[lb * 2];
    const float denom = fmaxf(mm_[lb * 2 + 1] - mn, 1e-4f);
    const float rden = 1.0f / denom;

    floatx4 acc[2][8];
#pragma unroll
    for (int a = 0; a < 2; ++a)
#pragma unroll
        for (int n = 0; n < 8; ++n) acc[a][n] = (floatx4){0.f, 0.f, 0.f, 0.f};

    const short* Ab = pp2 + (size_t)lb * 128 * KPAD;
    const short* Bb = fxb + (size_t)lb * 128 * KPAD;

    for (int it = 0; it < 8; ++it) {
        const int kk = kc * 512 + it * 64;
        if (kk >= KTOT) break;
        // stage A (with fused pmap) and B: 128 rows x 8 short8 each
        for (int e = tid; e < 2048; e += 256) {
            const bool isA = (e < 1024);
            const int e2 = isA ? e : e - 1024;
            const int row = e2 >> 3, i8 = e2 & 7;
            const int k = kk + i8 * 8;
            const short* src = (isA ? Ab : Bb) + (size_t)row * KPAD + k;
            short8 v = {0, 0, 0, 0, 0, 0, 0, 0};
            if (k + 8 <= KTOT) {
                v = *reinterpret_cast<const short8*>(src);
            } else {
#pragma unroll
                for (int j = 0; j < 8; ++j) v[j] = (k + j < KTOT) ? src[j] : (short)0;
            }
            if (isA) {
#pragma unroll
                for (int j = 0; j < 8; ++j) {
                    if (k + j < KTOT) {
                        float f = (b2f(v[j]) - mn) * rden;
                        v[j] = f2bf(1.0f / (1.0f + expf(-10.0f * (f - 0.5f))));
                    } else v[j] = 0;
                }
                *reinterpret_cast<short8*>(&As[row * AP + i8 * 8]) = v;
            } else {
                *reinterpret_cast<short8*>(&Bs[row * AP + i8 * 8]) = v;
            }
        }
        __syncthreads();
#pragma unroll
        for (int ks = 0; ks < 2; ++ks) {
            short8 af0 = *reinterpret_cast<const short8*>(&As[((2 * wave) * 16 + mm) * AP + ks * 32 + q * 8]);
            short8 af1 = *reinterpret_cast<const short8*>(&As[((2 * wave + 1) * 16 + mm) * AP + ks * 32 + q * 8]);
#pragma unroll
            for (int n = 0; n < 8; ++n) {
                short8 bf = *reinterpret_cast<const short8*>(&Bs[(n * 16 + mm) * AP + ks * 32 + q * 8]);
                acc[0][n] = __builtin_amdgcn_mfma_f32_16x16x32_bf16(af0, bf, acc[0][n], 0, 0, 0);
                acc[1][n] = __builtin_amdgcn_mfma_f32_16x16x32_bf16(af1, bf, acc[1][n], 0, 0, 0);
            }
        }
        __syncthreads();
    }

    float* base = px_part + ((size_t)kc * gb + lb) * EL_PX;
#pragma unroll
    for (int a = 0; a < 2; ++a) {
        const int gm0 = (2 * wave + a) * 16 + q * 4;
#pragma unroll
        for (int n = 0; n < 8; ++n) {
            const int gn = n * 16 + mm;
#pragma unroll
            for (int r = 0; r < 4; ++r)
                base[(size_t)(gm0 + r) * 128 + gn] = acc[a][n][r];
        }
    }
}

// ---------------------------------------------------------------------------
// K11b: reduce the NKC partials -> px (applies 1/3690)
// ---------------------------------------------------------------------------
__global__ __launch_bounds__(256) void px_reduce(const float* __restrict__ part,
                                                 float* __restrict__ px,
                                                 int gb) {
    int i = blockIdx.x * 256 + threadIdx.x;
    if (i >= gb * EL_PX) return;
    int lb = i / EL_PX;
    int r = i % EL_PX;
    float s = 0.0f;
#pragma unroll
    for (int kc = 0; kc < NKC; ++kc)
        s += part[((size_t)kc * gb + lb) * EL_PX + r];
    px[i] = s * (1.0f / (float)KTOT);
}

// ---------------------------------------------------------------------------
// K12: FC -> f32 out
// ---------------------------------------------------------------------------
__global__ __launch_bounds__(256) void fc_k(const float* __restrict__ px,
                                            const float* __restrict__ w,
                                            const float* __restrict__ bias,
                                            float* __restrict__ out,
                                            int b0) {
    const int gw = blockIdx.x * 4 + (threadIdx.x >> 6);
    const int lane = threadIdx.x & 63;
    const int lb = gw >> 8;
    const int o = gw & 255;
    const float* xb = px + (size_t)lb * EL_PX;
    const float* wr = w + (size_t)o * EL_PX;
    float s = 0.0f;
    for (int k = lane; k < EL_PX; k += 64) s += xb[k] * wr[k];
#pragma unroll
    for (int off = 32; off > 0; off >>= 1) s += __shfl_down(s, off);
    if (lane == 0) out[(size_t)(b0 + lb) * 256 + o] = s + bias[o];
}

// ---------------------------------------------------------------------------
extern "C" void kernel_launch(void* const* d_in, const int* in_sizes, int n_in,
                              void* d_out, int out_size, void* d_ws, size_t ws_size,
                              hipStream_t stream) {
    const float* x_t   = (const float*)d_in[0];
    const float* image = (const float*)d_in[1];
    const float* c1_w  = (const float*)d_in[2];
    const float* c1_b  = (const float*)d_in[3];
    const float* bn1_g = (const float*)d_in[4];
    const float* bn1_b = (const float*)d_in[5];
    const float* c2_w  = (const float*)d_in[6];
    const float* c2_b  = (const float*)d_in[7];
    const float* bn2_g = (const float*)d_in[8];
    const float* bn2_b = (const float*)d_in[9];
    const float* a1_w  = (const float*)d_in[10];
    const float* a1_b  = (const float*)d_in[11];
    const float* abn1_g= (const float*)d_in[12];
    const float* abn1_b= (const float*)d_in[13];
    const float* a2_w  = (const float*)d_in[14];
    const float* a2_b  = (const float*)d_in[15];
    const float* abn2_g= (const float*)d_in[16];
    const float* abn2_b= (const float*)d_in[17];
    const float* p1_w  = (const float*)d_in[18];
    const float* p1_b  = (const float*)d_in[19];
    const float* pbn1_g= (const float*)d_in[20];
    const float* pbn1_b= (const float*)d_in[21];
    const float* p2_w  = (const float*)d_in[22];
    const float* p2_b  = (const float*)d_in[23];
    const float* pbn2_g= (const float*)d_in[24];
    const float* pbn2_b= (const float*)d_in[25];
    const float* fc_w  = (const float*)d_in[26];
    const float* fc_b  = (const float*)d_in[27];
    float* outp = (float*)d_out;

    // Fixed region: folded bf16 weights + biases
    float* ws = (float*)d_ws;
    short* wTa1 = (short*)ws;
    short* wTa2 = wTa1 + WSH_A1;
    short* wTp1 = wTa2 + WSH_A2;
    short* wTp2 = wTp1 + WSH_A1;
    short* wTc2 = wTp2 + WSH_A2;
    float* bfa1 = ws + WSH_TOT / 2;
    float* bfa2 = bfa1 + 128;
    float* bfp1 = bfa2 + 128;
    float* bfp2 = bfp1 + 128;
    float* bfc2 = bfp2 + 128;
    float* dyn  = bfc2 + 128;
    const size_t fixed_floats = WSH_TOT / 2 + 1024;

    int GB = 32;
    while (GB > 1) {
        size_t need = ((size_t)GB * EL_PER_BATCH + fixed_floats + 256) * sizeof(float);
        if (need <= ws_size) break;
        GB >>= 1;
    }
    const int ngroups = NB / GB;

    float* heat = dyn;                                 // GB*EL_HEAT
    float* m    = heat + (size_t)GB * EL_HEAT;         // 64
    float* regB = m + 64;                              // GB*EL_REGB
    float* regC = regB + (size_t)GB * EL_REGB;         // GB*EL_REGC
    float* regD = regC + (size_t)GB * EL_REGC;         // GB*EL_REGD
    float* regE = regD + (size_t)GB * EL_REGD;         // GB*EL_REGE
    float* pmm  = regE + (size_t)GB * EL_REGE;         // 128
    float* px   = pmm + 128;                           // GB*EL_PX

    float* G      = regD;            // [lb][181][330] f32 (dead after rowcombine)
    short* out1b  = (short*)regB;    // bf16 ch-last [H1*W1][32]
    short* out2b  = (short*)regC;    // bf16 ch-last [pixel][64]
    short* fbuf   = (short*)regD;    // bf16 ch-last [pixel][128] (a1 out)
    short* fxbf   = (short*)regE;    // bf16 ch-first [c][KPAD]
    short* pp1    = (short*)regB;    // bf16 ch-last (out1 dead)
    short* pp2    = (short*)regD;    // bf16 ch-first [c][KPAD] (fbuf dead)
    float* pxpart = regB;            // f32, NKC*GB*EL_PX (pp1 dead after p2 conv)

    wfold_k<<<(9 * 128 * CH2 + 255) / 256, 256, 0, stream>>>(a1_w, abn1_g, a1_b, abn1_b, wTa1, bfa1, 128, CH2);
    wfold_k<<<(9 * 128 * CH3 + 255) / 256, 256, 0, stream>>>(a2_w, abn2_g, a2_b, abn2_b, wTa2, bfa2, 128, CH3);
    wfold_k<<<(9 * 128 * CH2 + 255) / 256, 256, 0, stream>>>(p1_w, pbn1_g, p1_b, pbn1_b, wTp1, bfp1, 128, CH2);
    wfold_k<<<(9 * 128 * CH3 + 255) / 256, 256, 0, stream>>>(p2_w, pbn2_g, p2_b, pbn2_b, wTp2, bfp2, 128, CH3);
    wfold_k<<<(9 * 64 * 32 + 255) / 256, 256, 0, stream>>>(c2_w, bn2_g, c2_b, bn2_b, wTc2, bfc2, 64, 32);

    const int hblocks = (EL_HEAT + 255) / 256;    // 233

    for (int gidx = 0; gidx < ngroups; ++gidx) {
        const int b0 = gidx * GB;
        mm_init<<<1, 256, 0, stream>>>((unsigned*)m, (unsigned*)pmm);
        heat_scatter_cols<<<dim3(NSTRIP, GB), 256, 0, stream>>>(x_t, G, b0);
        heat_rowcombine<<<dim3(hblocks, GB), 256, 0, stream>>>(G, heat, (unsigned*)m);
        conv1_pool<<<(GB * H1 * W1 + 255) / 256, 256, 0, stream>>>(
            heat, image, m, c1_w, c1_b, bn1_g, bn1_b, out1b, b0, GB);
        conv2_mfma<<<dim3(6, 12, GB), 256, 0, stream>>>(out1b, wTc2, bfc2, out2b);
        conv3x3_mfma<CH2, false, 0><<<dim3(3, 12, GB), 256, 0, stream>>>(out2b, wTa1, bfa1, fbuf);
        conv3x3_mfma<CH3, true,  2><<<dim3(3, 12, GB), 256, 0, stream>>>(fbuf, wTa2, bfa2, fxbf);
        conv3x3_mfma<CH2, false, 0><<<dim3(3, 12, GB), 256, 0, stream>>>(out2b, wTp1, bfp1, pp1);
        conv3x3_mfma<CH3, false, 2><<<dim3(3, 12, GB), 256, 0, stream>>>(pp1, wTp2, bfp2, pp2);
        pminmax<<<dim3(128, GB), 256, 0, stream>>>(pp2, (unsigned*)pmm);
        // K-split einsum (pmap fused into A staging) + reduction
        einsum_part<<<dim3(NKC, GB), 256, 0, stream>>>(pp2, fxbf, pmm, pxpart);
        px_reduce<<<(GB * EL_PX + 255) / 256, 256, 0, stream>>>(pxpart, px, GB);
        fc_k<<<GB * 64, 256, 0, stream>>>(px, fc_w, fc_b, outp, b0);
    }
}

// Round 14
// 766.637 us; speedup vs baseline: 2.6724x; 1.0686x over previous
//
#include <hip/hip_runtime.h>
#include <hip/hip_bf16.h>

// Problem constants
#define NB 32
#define NT 1024
#define IH 180
#define IW 330
#define KSZ 37
#define XBINS 181
#define H1 90
#define W1 165
#define H2 45
#define W2 82
#define PIX2 (H2*W2)          // 3690
#define KTOT PIX2
#define KPAD 3712
#define CH1 32
#define CH2 64
#define CH3 128
#define NSTRIP 6
#define NKC 8                 // einsum K-chunks (512 each over KPAD)

// Per-batch f32-slot counts
#define EL_HEAT (IH*IW)           // 59,400
#define EL_REGB 237600            // out1 bf16 [H1*W1][32] -> pp1 bf16 [PIX2][128] -> px_part f32
#define EL_REGC (CH2*PIX2/2)      // 118,080 : out2 bf16 ch-last [pixel][64]
#define EL_REGD (CH3*KPAD/2)      // 237,568 : G f32 -> fbuf bf16 -> pp2 bf16 [c][KPAD]
#define EL_REGE (CH3*KPAD/2)      // 237,568 : fx bf16 [c][KPAD]
#define EL_PX   (CH3*CH3)         // 16,384
#define EL_PER_BATCH (EL_HEAT + EL_REGB + EL_REGC + EL_REGD + EL_REGE + EL_PX) // 906,600

// folded-weight sizes (bf16 shorts)
#define WSH_A1 (9*128*64)
#define WSH_A2 (9*128*128)
#define WSH_C2 (9*64*32)
#define WSH_TOT (2*WSH_A1 + 2*WSH_A2 + WSH_C2)

typedef __attribute__((ext_vector_type(8))) short short8;
typedef __attribute__((ext_vector_type(4))) float floatx4;

__device__ __forceinline__ short f2bf(float v) {
    __hip_bfloat16 h = __float2bfloat16(v);
    return *reinterpret_cast<short*>(&h);
}
__device__ __forceinline__ float b2f(short s) {
    __hip_bfloat16 h = *reinterpret_cast<__hip_bfloat16*>(&s);
    return __bfloat162float(h);
}

// ---------------------------------------------------------------------------
__global__ __launch_bounds__(256) void mm_init(unsigned* __restrict__ m_bits,
                                               unsigned* __restrict__ pmm_bits) {
    int i = threadIdx.x;
    if (i < 64) {
        m_bits[i] = 0u;
        pmm_bits[2 * i]     = 0x7F800000u;   // +inf
        pmm_bits[2 * i + 1] = 0u;
    }
}

// ---------------------------------------------------------------------------
// S1: separable scatter — column profiles into G[xp][Y]
// ---------------------------------------------------------------------------
__global__ __launch_bounds__(256) void heat_scatter_cols(const float* __restrict__ x_t,
                                                         float* __restrict__ G,
                                                         int b0) {
    const int strip = blockIdx.x;
    const int lb = blockIdx.y;
    const int b = b0 + lb;
    const int c0 = strip * 64;
    const int cw = min(64, IW - c0);
    __shared__ float g[XBINS * 64];
    __shared__ float k1n[64];
    __shared__ float2 pts[NT];
    const int tid = threadIdx.x;

    if (tid < 64) {
        float v = 0.0f;
        if (tid < KSZ) {
            float ax = (float)tid - 18.0f;
            v = expf(-ax * ax / 18.0f);
        }
        k1n[tid] = v;
    }
    for (int i = tid; i < XBINS * 64; i += 256) g[i] = 0.0f;
    {
        const float2* xb = (const float2*)x_t + (size_t)b * NT;
        for (int i = tid; i < NT; i += 256) pts[i] = xb[i];
    }
    __syncthreads();
    if (tid == 0) {
        float s = 0.0f;
        for (int i = 0; i < KSZ; i++) s += k1n[i];
        float inv = 1.0f / s;
        for (int i = 0; i < KSZ; i++) k1n[i] *= inv;
    }
    __syncthreads();

    const int wave = tid >> 6;
    const int lane = tid & 63;
    const float kc = k1n[lane];

    for (int p = wave; p < NT; p += 4) {
        float x = pts[p].x, y = pts[p].y;
        if (isnan(x) || isnan(y)) continue;
        int xp = IH - (int)((x - 30.0f) * 180.0f);
        xp = min(max(xp, 0), 180);
        int yp = (int)((y - 120.0f) * 165.0f);
        int ys = min(max(yp - 18, 0), IW - 36);
        int ye = min(max(yp + 18, 0), IW);
        int nc = ye - ys;
        int col = ys + lane;
        if (lane < nc && col >= c0 && col < c0 + cw)
            atomicAdd(&g[xp * 64 + col - c0], kc);
    }
    __syncthreads();
    for (int i = tid; i < XBINS * cw; i += 256) {
        int row = i / cw, col = i % cw;
        G[((size_t)lb * XBINS + row) * IW + c0 + col] = g[row * 64 + col];
    }
}

// ---------------------------------------------------------------------------
// S2: row-combine + fused per-batch max
// ---------------------------------------------------------------------------
__global__ __launch_bounds__(256) void heat_rowcombine(const float* __restrict__ G,
                                                       float* __restrict__ heat,
                                                       unsigned* __restrict__ m_bits) {
    const int lb = blockIdx.y;
    const int tid = threadIdx.x;
    __shared__ float k1n[64];
    if (tid < 64) {
        float v = 0.0f;
        if (tid < KSZ) {
            float ax = (float)tid - 18.0f;
            v = expf(-ax * ax / 18.0f);
        }
        k1n[tid] = v;
    }
    __syncthreads();
    if (tid == 0) {
        float s = 0.0f;
        for (int i = 0; i < KSZ; i++) s += k1n[i];
        float inv = 1.0f / s;
        for (int i = 0; i < KSZ; i++) k1n[i] *= inv;
    }
    __syncthreads();

    const int idx = blockIdx.x * 256 + tid;
    float s = 0.0f;
    if (idx < EL_HEAT) {
        int X = idx / IW, Y = idx % IW;
        int lo = max(0, X - 17);
        int hi = (X >= IH - 36) ? 180 : X + 18;
        const float* Gb = G + (size_t)lb * XBINS * IW + Y;
        for (int xp = lo; xp <= hi; ++xp) {
            int xs = min(max(xp - 18, 0), IH - 36);
            s += k1n[X - xs] * Gb[(size_t)xp * IW];
        }
        heat[(size_t)lb * EL_HEAT + idx] = s;
    }
    __shared__ float red[256];
    red[tid] = s;
    __syncthreads();
    for (int st = 128; st > 0; st >>= 1) {
        if (tid < st) red[tid] = fmaxf(red[tid], red[tid + st]);
        __syncthreads();
    }
    if (tid == 0) atomicMax(&m_bits[lb], __float_as_uint(red[0]));
}

// ---------------------------------------------------------------------------
// K3: conv1(1->32) + BN + relu + pool (fuse folded); out bf16 ch-last [pix][32]
// ---------------------------------------------------------------------------
__global__ __launch_bounds__(256) void conv1_pool(const float* __restrict__ heat,
                                                  const float* __restrict__ image,
                                                  const float* __restrict__ m,
                                                  const float* __restrict__ w,
                                                  const float* __restrict__ cb,
                                                  const float* __restrict__ g,
                                                  const float* __restrict__ bb,
                                                  short* __restrict__ out1,
                                                  int b0, int gb) {
    __shared__ float ws_[CH1 * 9];
    __shared__ float bs_[CH1];
    const int tid = threadIdx.x;
    for (int i = tid; i < CH1 * 9; i += 256) {
        int oc = i / 9;
        ws_[i] = w[i] * g[oc];
    }
    if (tid < CH1) bs_[tid] = cb[tid] * g[tid] + bb[tid];
    __syncthreads();

    int t = blockIdx.x * 256 + tid;
    if (t >= gb * H1 * W1) return;
    int lb = t / (H1 * W1);
    int r = t % (H1 * W1);
    int py = r / W1, px = r % W1;
    const float s = 0.7f / (m[lb] + 1e-10f);
    const float* hb = heat + (size_t)lb * EL_HEAT;
    const float* ib = image + (size_t)(b0 + lb) * EL_HEAT;

    float v[4][4];
    int y0 = 2 * py - 1, x0 = 2 * px - 1;
#pragma unroll
    for (int i = 0; i < 4; i++) {
#pragma unroll
        for (int j = 0; j < 4; j++) {
            int y = y0 + i, x = x0 + j;
            float val = 0.0f;
            if (y >= 0 && y < IH && x >= 0 && x < IW) {
                size_t idx = (size_t)y * IW + x;
                val = s * hb[idx] + 0.3f * ib[idx];
            }
            v[i][j] = val;
        }
    }
    short8 pk[4];
#pragma unroll
    for (int oc = 0; oc < CH1; oc++) {
        float a00 = 0, a01 = 0, a10 = 0, a11 = 0;
        const float* wp = &ws_[oc * 9];
#pragma unroll
        for (int ky = 0; ky < 3; ky++) {
#pragma unroll
            for (int kx = 0; kx < 3; kx++) {
                float wv = wp[ky * 3 + kx];
                a00 += wv * v[ky][kx];
                a01 += wv * v[ky][kx + 1];
                a10 += wv * v[ky + 1][kx];
                a11 += wv * v[ky + 1][kx + 1];
            }
        }
        float bias = bs_[oc];
        a00 = fmaxf(a00 + bias, 0.0f);
        a01 = fmaxf(a01 + bias, 0.0f);
        a10 = fmaxf(a10 + bias, 0.0f);
        a11 = fmaxf(a11 + bias, 0.0f);
        pk[oc >> 3][oc & 7] = f2bf(fmaxf(fmaxf(a00, a01), fmaxf(a10, a11)));
    }
    short8* op = reinterpret_cast<short8*>(&out1[((size_t)lb * H1 * W1 + r) * CH1]);
#pragma unroll
    for (int vv = 0; vv < 4; vv++) op[vv] = pk[vv];
}

// ---------------------------------------------------------------------------
// weight fold/transpose: wT[tap][oc][ic] = bf16(w[oc][ic][tap]*g[oc])
// ---------------------------------------------------------------------------
__global__ __launch_bounds__(256) void wfold_k(const float* __restrict__ w,
                                               const float* __restrict__ g,
                                               const float* __restrict__ cb,
                                               const float* __restrict__ bb,
                                               short* __restrict__ wT,
                                               float* __restrict__ bfold,
                                               int OC, int IC) {
    int i = blockIdx.x * 256 + threadIdx.x;
    int n = 9 * OC * IC;
    if (i >= n) return;
    int tap = i / (OC * IC);
    int r = i % (OC * IC);
    int oc = r / IC;
    int ic = r % IC;
    wT[i] = f2bf(w[((size_t)oc * IC + ic) * 9 + tap] * g[oc]);
    if (tap == 0 && ic == 0) bfold[oc] = cb[oc] * g[oc] + bb[oc];
}

// ---------------------------------------------------------------------------
// K4: conv2(32->64) + BN + relu + 2x2 pool via bf16 MFMA.
// LDS-staged epilogue: pooled C-tile [64 px][72] -> coalesced short8 stores.
// ---------------------------------------------------------------------------
__global__ __launch_bounds__(256) void conv2_mfma(const short* __restrict__ in,
                                                  const short* __restrict__ wT,
                                                  const float* __restrict__ bfold,
                                                  short* __restrict__ out) {
    const int xt = blockIdx.x;   // 0..5 : 32 pre-pool cols
    const int yt = blockIdx.y;   // 0..11: 8 pre-pool rows
    const int lb = blockIdx.z;
    const int x0 = xt * 32, y0 = yt * 8;
    const int tid = threadIdx.x;
    const int wave = tid >> 6, lane = tid & 63;
    const int mm = lane & 15, q = lane >> 4;
    constexpr int AP = 40;
    constexpr int CP = 72;                      // C-stage stride (16B-aligned rows)
    __shared__ __align__(16) short smem[10 * 34 * AP];   // 27,200 B (>= 64*CP=9,216)

    floatx4 acc[2][2][4];
#pragma unroll
    for (int a = 0; a < 2; ++a)
#pragma unroll
        for (int bq = 0; bq < 2; ++bq)
#pragma unroll
            for (int j = 0; j < 4; ++j) acc[a][bq][j] = (floatx4){0.f, 0.f, 0.f, 0.f};

    const short* inb = in + (size_t)lb * (H1 * W1) * CH1;
    for (int e = tid; e < 10 * 34 * 4; e += 256) {
        int dy = e / (34 * 4);
        int r = e % (34 * 4);
        int tx = r / 4;
        int i8 = r % 4;
        int yin = y0 + dy - 1, xin = x0 + tx - 1;
        short8 hv = {0, 0, 0, 0, 0, 0, 0, 0};
        if (yin >= 0 && yin < H1 && xin >= 0 && xin < W1)
            hv = *reinterpret_cast<const short8*>(&inb[((size_t)(yin * W1 + xin)) * CH1 + i8 * 8]);
        *reinterpret_cast<short8*>(&smem[(dy * 34 + tx) * AP + i8 * 8]) = hv;
    }
    __syncthreads();

#pragma unroll
    for (int tap = 0; tap < 9; ++tap) {
        const int dy = tap / 3, dx = tap % 3;
        short8 bf[4];
#pragma unroll
        for (int j = 0; j < 4; ++j)
            bf[j] = *reinterpret_cast<const short8*>(&wT[((size_t)tap * 64 + j * 16 + mm) * 32 + q * 8]);
#pragma unroll
        for (int row = 0; row < 2; ++row) {
#pragma unroll
            for (int xh = 0; xh < 2; ++xh) {
                short8 af = *reinterpret_cast<const short8*>(
                    &smem[((2 * wave + row + dy) * 34 + xh * 16 + dx + mm) * AP + q * 8]);
#pragma unroll
                for (int j = 0; j < 4; ++j)
                    acc[row][xh][j] = __builtin_amdgcn_mfma_f32_16x16x32_bf16(af, bf[j], acc[row][xh][j], 0, 0, 0);
            }
        }
    }
    __syncthreads();

    // stage pooled C into LDS: [local pooled pixel 0..63][CP]
    short* cst = smem;
#pragma unroll
    for (int xh = 0; xh < 2; ++xh) {
#pragma unroll
        for (int j = 0; j < 4; ++j) {
            const float bias = bfold[j * 16 + mm];
#pragma unroll
            for (int rp = 0; rp < 2; ++rp) {
                int pxl = xh * 8 + q * 2 + rp;            // 0..15
                float v = fmaxf(fmaxf(acc[0][xh][j][2 * rp], acc[0][xh][j][2 * rp + 1]),
                                fmaxf(acc[1][xh][j][2 * rp], acc[1][xh][j][2 * rp + 1]));
                v = fmaxf(v + bias, 0.0f);
                cst[(wave * 16 + pxl) * CP + j * 16 + mm] = f2bf(v);
            }
        }
    }
    __syncthreads();

    // coalesced copy-out: 64 px x 8 short8
    short* ob = out + (size_t)lb * PIX2 * CH2;
    for (int e = tid; e < 512; e += 256) {
        int pl = e >> 3, c8 = e & 7;
        int py = yt * 4 + (pl >> 4);
        int pxg = xt * 16 + (pl & 15);
        if (py < H2 && pxg < W2)
            *reinterpret_cast<short8*>(&ob[((size_t)py * W2 + pxg) * CH2 + c8 * 8]) =
                *reinterpret_cast<const short8*>(&cst[pl * CP + c8 * 8]);
    }
}

// ---------------------------------------------------------------------------
// K5-K8: 3x3 conv via bf16 MFMA; bf16 ch-last input; 32x4 tile.
// LDS-staged epilogue. OM: 0 = bf16 ch-last out, 2 = bf16 ch-first [oc][KPAD].
// ---------------------------------------------------------------------------
template <int IC, bool SIG, int OM>
__global__ __launch_bounds__(256) void conv3x3_mfma(const short* __restrict__ in,
                                                    const short* __restrict__ wT,
                                                    const float* __restrict__ bfold,
                                                    short* __restrict__ outp) {
    const int xt = blockIdx.x;      // 0..2 (32 cols)
    const int yt = blockIdx.y;      // 0..11 (4 rows)
    const int lb = blockIdx.z;
    const int x0 = xt * 32, y0 = yt * 4;
    const int tid = threadIdx.x;
    const int wave = tid >> 6, lane = tid & 63;
    const int mm = lane & 15, q = lane >> 4;

    constexpr int KC = 32;
    constexpr int NCH = IC / KC;
    constexpr int AP = 40;
    constexpr int CP0 = 136;   // [pixel][128] stage stride (16B-aligned, 2-way banks)
    constexpr int CP2 = 132;   // [oc][pixel] stage stride (4B-aligned, distinct banks)
    // max(tileA 8160, OM0 128*136=17408, OM2 128*132=16896) shorts
    __shared__ __align__(16) short smem[17408];

    floatx4 acc[16];
#pragma unroll
    for (int i = 0; i < 16; ++i) acc[i] = (floatx4){0.f, 0.f, 0.f, 0.f};

    const short* inb = in + (size_t)lb * PIX2 * IC;

    for (int c = 0; c < NCH; ++c) {
        const int ic0 = c * KC;
        for (int e = tid; e < 6 * 34 * (KC / 8); e += 256) {
            int dy = e / (34 * (KC / 8));
            int r  = e % (34 * (KC / 8));
            int tx = r / (KC / 8);
            int i8 = r % (KC / 8);
            int yin = y0 + dy - 1, xin = x0 + tx - 1;
            short8 hv = {0, 0, 0, 0, 0, 0, 0, 0};
            if (yin >= 0 && yin < H2 && xin >= 0 && xin < W2)
                hv = *reinterpret_cast<const short8*>(
                    &inb[((size_t)(yin * W2 + xin)) * IC + ic0 + i8 * 8]);
            *reinterpret_cast<short8*>(&smem[(dy * 34 + tx) * AP + i8 * 8]) = hv;
        }
        __syncthreads();

        const int oc0 = wave * 32 + mm;
#pragma unroll
        for (int tap = 0; tap < 9; ++tap) {
            const int dy = tap / 3, dx = tap % 3;
            short8 b0 = *reinterpret_cast<const short8*>(
                &wT[((size_t)tap * 128 + oc0) * IC + ic0 + q * 8]);
            short8 b1 = *reinterpret_cast<const short8*>(
                &wT[((size_t)tap * 128 + oc0 + 16) * IC + ic0 + q * 8]);
#pragma unroll
            for (int t = 0; t < 8; ++t) {
                const int tr = t >> 1, tc = t & 1;
                short8 af = *reinterpret_cast<const short8*>(
                    &smem[((tr + dy) * 34 + tc * 16 + dx + mm) * AP + q * 8]);
                acc[t * 2]     = __builtin_amdgcn_mfma_f32_16x16x32_bf16(af, b0, acc[t * 2], 0, 0, 0);
                acc[t * 2 + 1] = __builtin_amdgcn_mfma_f32_16x16x32_bf16(af, b1, acc[t * 2 + 1], 0, 0, 0);
            }
        }
        __syncthreads();
    }

    // stage C into LDS
    const int oc0 = wave * 32 + mm;
    const float bias0 = bfold[oc0];
    const float bias1 = bfold[oc0 + 16];
    short* cst = smem;
#pragma unroll
    for (int t = 0; t < 8; ++t) {
        const int tr = t >> 1, tc = t & 1;
#pragma unroll
        for (int r = 0; r < 4; ++r) {
            int pl = tr * 32 + tc * 16 + q * 4 + r;       // 0..127
            float z0 = acc[t * 2][r] + bias0;
            float z1 = acc[t * 2 + 1][r] + bias1;
            if (SIG) {
                z0 = 1.0f / (1.0f + expf(-z0));
                z1 = 1.0f / (1.0f + expf(-z1));
            } else {
                z0 = fmaxf(z0, 0.0f);
                z1 = fmaxf(z1, 0.0f);
            }
            if (OM == 0) {
                cst[pl * CP0 + oc0] = f2bf(z0);
                cst[pl * CP0 + oc0 + 16] = f2bf(z1);
            } else {
                cst[oc0 * CP2 + pl] = f2bf(z0);
                cst[(oc0 + 16) * CP2 + pl] = f2bf(z1);
            }
        }
    }
    __syncthreads();

    if (OM == 0) {
        short* ob = outp + (size_t)lb * PIX2 * 128;
        for (int e = tid; e < 2048; e += 256) {
            int pl = e >> 4, c8 = e & 15;
            int yy = y0 + (pl >> 5), xx = x0 + (pl & 31);
            if (yy < H2 && xx < W2)
                *reinterpret_cast<short8*>(&ob[((size_t)yy * W2 + xx) * 128 + c8 * 8]) =
                    *reinterpret_cast<const short8*>(&cst[pl * CP0 + c8 * 8]);
        }
    } else {
        short* ob = outp + (size_t)lb * 128 * KPAD;
        for (int e = tid; e < 8192; e += 256) {
            int oc = e >> 6;                   // 0..127
            int r2 = e & 63;
            int yy4 = r2 >> 4;                 // 0..3
            int x2 = (r2 & 15) * 2;            // 0..30
            int yy = y0 + yy4, xx = x0 + x2;
            if (yy < H2 && xx < W2) {
                int pl = yy4 * 32 + x2;
                if (xx + 1 < W2) {
                    *reinterpret_cast<int*>(&ob[(size_t)oc * KPAD + yy * W2 + xx]) =
                        *reinterpret_cast<const int*>(&cst[oc * CP2 + pl]);
                } else {
                    ob[(size_t)oc * KPAD + yy * W2 + xx] = cst[oc * CP2 + pl];
                }
            }
        }
    }
}

// ---------------------------------------------------------------------------
// K9: per-batch min/max of pp2 (bf16 ch-first [c][KPAD], valid hw < PIX2)
// ---------------------------------------------------------------------------
__global__ __launch_bounds__(256) void pminmax(const short* __restrict__ p,
                                               unsigned* __restrict__ pmm_bits) {
    const int c = blockIdx.x;              // 0..127
    const int lb = blockIdx.y;
    const short* pb = p + (size_t)lb * 128 * KPAD + (size_t)c * KPAD;
    float mn = INFINITY, mx = 0.0f;
    for (int i = threadIdx.x; i < PIX2; i += 256) {
        float v = b2f(pb[i]);
        mn = fminf(mn, v);
        mx = fmaxf(mx, v);
    }
    __shared__ float rmn[256], rmx[256];
    rmn[threadIdx.x] = mn; rmx[threadIdx.x] = mx;
    __syncthreads();
    for (int s = 128; s > 0; s >>= 1) {
        if (threadIdx.x < s) {
            rmn[threadIdx.x] = fminf(rmn[threadIdx.x], rmn[threadIdx.x + s]);
            rmx[threadIdx.x] = fmaxf(rmx[threadIdx.x], rmx[threadIdx.x + s]);
        }
        __syncthreads();
    }
    if (threadIdx.x == 0) {
        atomicMin(&pmm_bits[lb * 2],     __float_as_uint(rmn[0]));
        atomicMax(&pmm_bits[lb * 2 + 1], __float_as_uint(rmx[0]));
    }
}

// ---------------------------------------------------------------------------
// K11a: K-split einsum via bf16 MFMA, pmap fused into A-staging.
// ---------------------------------------------------------------------------
__global__ __launch_bounds__(256) void einsum_part(const short* __restrict__ pp2,
                                                   const short* __restrict__ fxb,
                                                   const float* __restrict__ mm_,
                                                   float* __restrict__ px_part) {
    const int kc = blockIdx.x;   // 0..NKC-1
    const int lb = blockIdx.y;
    const int gb = gridDim.y;
    const int tid = threadIdx.x;
    const int wave = tid >> 6, lane = tid & 63;
    const int mm = lane & 15, q = lane >> 4;
    constexpr int AP = 72;
    __shared__ __align__(16) short As[128 * AP];
    __shared__ __align__(16) short Bs[128 * AP];

    const float mn = mm_[lb * 2];
    const float denom = fmaxf(mm_[lb * 2 + 1] - mn, 1e-4f);
    const float rden = 1.0f / denom;

    floatx4 acc[2][8];
#pragma unroll
    for (int a = 0; a < 2; ++a)
#pragma unroll
        for (int n = 0; n < 8; ++n) acc[a][n] = (floatx4){0.f, 0.f, 0.f, 0.f};

    const short* Ab = pp2 + (size_t)lb * 128 * KPAD;
    const short* Bb = fxb + (size_t)lb * 128 * KPAD;

    for (int it = 0; it < 8; ++it) {
        const int kk = kc * 512 + it * 64;
        if (kk >= KTOT) break;
        for (int e = tid; e < 2048; e += 256) {
            const bool isA = (e < 1024);
            const int e2 = isA ? e : e - 1024;
            const int row = e2 >> 3, i8 = e2 & 7;
            const int k = kk + i8 * 8;
            const short* src = (isA ? Ab : Bb) + (size_t)row * KPAD + k;
            short8 v = {0, 0, 0, 0, 0, 0, 0, 0};
            if (k + 8 <= KTOT) {
                v = *reinterpret_cast<const short8*>(src);
            } else {
#pragma unroll
                for (int j = 0; j < 8; ++j) v[j] = (k + j < KTOT) ? src[j] : (short)0;
            }
            if (isA) {
#pragma unroll
                for (int j = 0; j < 8; ++j) {
                    if (k + j < KTOT) {
                        float f = (b2f(v[j]) - mn) * rden;
                        v[j] = f2bf(1.0f / (1.0f + expf(-10.0f * (f - 0.5f))));
                    } else v[j] = 0;
                }
                *reinterpret_cast<short8*>(&As[row * AP + i8 * 8]) = v;
            } else {
                *reinterpret_cast<short8*>(&Bs[row * AP + i8 * 8]) = v;
            }
        }
        __syncthreads();
#pragma unroll
        for (int ks = 0; ks < 2; ++ks) {
            short8 af0 = *reinterpret_cast<const short8*>(&As[((2 * wave) * 16 + mm) * AP + ks * 32 + q * 8]);
            short8 af1 = *reinterpret_cast<const short8*>(&As[((2 * wave + 1) * 16 + mm) * AP + ks * 32 + q * 8]);
#pragma unroll
            for (int n = 0; n < 8; ++n) {
                short8 bf = *reinterpret_cast<const short8*>(&Bs[(n * 16 + mm) * AP + ks * 32 + q * 8]);
                acc[0][n] = __builtin_amdgcn_mfma_f32_16x16x32_bf16(af0, bf, acc[0][n], 0, 0, 0);
                acc[1][n] = __builtin_amdgcn_mfma_f32_16x16x32_bf16(af1, bf, acc[1][n], 0, 0, 0);
            }
        }
        __syncthreads();
    }

    float* base = px_part + ((size_t)kc * gb + lb) * EL_PX;
#pragma unroll
    for (int a = 0; a < 2; ++a) {
        const int gm0 = (2 * wave + a) * 16 + q * 4;
#pragma unroll
        for (int n = 0; n < 8; ++n) {
            const int gn = n * 16 + mm;
#pragma unroll
            for (int r = 0; r < 4; ++r)
                base[(size_t)(gm0 + r) * 128 + gn] = acc[a][n][r];
        }
    }
}

// ---------------------------------------------------------------------------
// K11b: reduce the NKC partials -> px (applies 1/3690)
// ---------------------------------------------------------------------------
__global__ __launch_bounds__(256) void px_reduce(const float* __restrict__ part,
                                                 float* __restrict__ px,
                                                 int gb) {
    int i = blockIdx.x * 256 + threadIdx.x;
    if (i >= gb * EL_PX) return;
    int lb = i / EL_PX;
    int r = i % EL_PX;
    float s = 0.0f;
#pragma unroll
    for (int kc = 0; kc < NKC; ++kc)
        s += part[((size_t)kc * gb + lb) * EL_PX + r];
    px[i] = s * (1.0f / (float)KTOT);
}

// ---------------------------------------------------------------------------
// K12: FC -> f32 out
// ---------------------------------------------------------------------------
__global__ __launch_bounds__(256) void fc_k(const float* __restrict__ px,
                                            const float* __restrict__ w,
                                            const float* __restrict__ bias,
                                            float* __restrict__ out,
                                            int b0) {
    const int gw = blockIdx.x * 4 + (threadIdx.x >> 6);
    const int lane = threadIdx.x & 63;
    const int lb = gw >> 8;
    const int o = gw & 255;
    const float* xb = px + (size_t)lb * EL_PX;
    const float* wr = w + (size_t)o * EL_PX;
    float s = 0.0f;
    for (int k = lane; k < EL_PX; k += 64) s += xb[k] * wr[k];
#pragma unroll
    for (int off = 32; off > 0; off >>= 1) s += __shfl_down(s, off);
    if (lane == 0) out[(size_t)(b0 + lb) * 256 + o] = s + bias[o];
}

// ---------------------------------------------------------------------------
extern "C" void kernel_launch(void* const* d_in, const int* in_sizes, int n_in,
                              void* d_out, int out_size, void* d_ws, size_t ws_size,
                              hipStream_t stream) {
    const float* x_t   = (const float*)d_in[0];
    const float* image = (const float*)d_in[1];
    const float* c1_w  = (const float*)d_in[2];
    const float* c1_b  = (const float*)d_in[3];
    const float* bn1_g = (const float*)d_in[4];
    const float* bn1_b = (const float*)d_in[5];
    const float* c2_w  = (const float*)d_in[6];
    const float* c2_b  = (const float*)d_in[7];
    const float* bn2_g = (const float*)d_in[8];
    const float* bn2_b = (const float*)d_in[9];
    const float* a1_w  = (const float*)d_in[10];
    const float* a1_b  = (const float*)d_in[11];
    const float* abn1_g= (const float*)d_in[12];
    const float* abn1_b= (const float*)d_in[13];
    const float* a2_w  = (const float*)d_in[14];
    const float* a2_b  = (const float*)d_in[15];
    const float* abn2_g= (const float*)d_in[16];
    const float* abn2_b= (const float*)d_in[17];
    const float* p1_w  = (const float*)d_in[18];
    const float* p1_b  = (const float*)d_in[19];
    const float* pbn1_g= (const float*)d_in[20];
    const float* pbn1_b= (const float*)d_in[21];
    const float* p2_w  = (const float*)d_in[22];
    const float* p2_b  = (const float*)d_in[23];
    const float* pbn2_g= (const float*)d_in[24];
    const float* pbn2_b= (const float*)d_in[25];
    const float* fc_w  = (const float*)d_in[26];
    const float* fc_b  = (const float*)d_in[27];
    float* outp = (float*)d_out;

    // Fixed region: folded bf16 weights + biases
    float* ws = (float*)d_ws;
    short* wTa1 = (short*)ws;
    short* wTa2 = wTa1 + WSH_A1;
    short* wTp1 = wTa2 + WSH_A2;
    short* wTp2 = wTp1 + WSH_A1;
    short* wTc2 = wTp2 + WSH_A2;
    float* bfa1 = ws + WSH_TOT / 2;
    float* bfa2 = bfa1 + 128;
    float* bfp1 = bfa2 + 128;
    float* bfp2 = bfp1 + 128;
    float* bfc2 = bfp2 + 128;
    float* dyn  = bfc2 + 128;
    const size_t fixed_floats = WSH_TOT / 2 + 1024;

    int GB = 32;
    while (GB > 1) {
        size_t need = ((size_t)GB * EL_PER_BATCH + fixed_floats + 256) * sizeof(float);
        if (need <= ws_size) break;
        GB >>= 1;
    }
    const int ngroups = NB / GB;

    float* heat = dyn;                                 // GB*EL_HEAT
    float* m    = heat + (size_t)GB * EL_HEAT;         // 64
    float* regB = m + 64;                              // GB*EL_REGB
    float* regC = regB + (size_t)GB * EL_REGB;         // GB*EL_REGC
    float* regD = regC + (size_t)GB * EL_REGC;         // GB*EL_REGD
    float* regE = regD + (size_t)GB * EL_REGD;         // GB*EL_REGE
    float* pmm  = regE + (size_t)GB * EL_REGE;         // 128
    float* px   = pmm + 128;                           // GB*EL_PX

    float* G      = regD;            // [lb][181][330] f32 (dead after rowcombine)
    short* out1b  = (short*)regB;    // bf16 ch-last [H1*W1][32]
    short* out2b  = (short*)regC;    // bf16 ch-last [pixel][64]
    short* fbuf   = (short*)regD;    // bf16 ch-last [pixel][128] (a1 out)
    short* fxbf   = (short*)regE;    // bf16 ch-first [c][KPAD]
    short* pp1    = (short*)regB;    // bf16 ch-last (out1 dead)
    short* pp2    = (short*)regD;    // bf16 ch-first [c][KPAD] (fbuf dead)
    float* pxpart = regB;            // f32, NKC*GB*EL_PX (pp1 dead after p2 conv)

    wfold_k<<<(9 * 128 * CH2 + 255) / 256, 256, 0, stream>>>(a1_w, abn1_g, a1_b, abn1_b, wTa1, bfa1, 128, CH2);
    wfold_k<<<(9 * 128 * CH3 + 255) / 256, 256, 0, stream>>>(a2_w, abn2_g, a2_b, abn2_b, wTa2, bfa2, 128, CH3);
    wfold_k<<<(9 * 128 * CH2 + 255) / 256, 256, 0, stream>>>(p1_w, pbn1_g, p1_b, pbn1_b, wTp1, bfp1, 128, CH2);
    wfold_k<<<(9 * 128 * CH3 + 255) / 256, 256, 0, stream>>>(p2_w, pbn2_g, p2_b, pbn2_b, wTp2, bfp2, 128, CH3);
    wfold_k<<<(9 * 64 * 32 + 255) / 256, 256, 0, stream>>>(c2_w, bn2_g, c2_b, bn2_b, wTc2, bfc2, 64, 32);

    const int hblocks = (EL_HEAT + 255) / 256;    // 233

    for (int gidx = 0; gidx < ngroups; ++gidx) {
        const int b0 = gidx * GB;
        mm_init<<<1, 256, 0, stream>>>((unsigned*)m, (unsigned*)pmm);
        heat_scatter_cols<<<dim3(NSTRIP, GB), 256, 0, stream>>>(x_t, G, b0);
        heat_rowcombine<<<dim3(hblocks, GB), 256, 0, stream>>>(G, heat, (unsigned*)m);
        conv1_pool<<<(GB * H1 * W1 + 255) / 256, 256, 0, stream>>>(
            heat, image, m, c1_w, c1_b, bn1_g, bn1_b, out1b, b0, GB);
        conv2_mfma<<<dim3(6, 12, GB), 256, 0, stream>>>(out1b, wTc2, bfc2, out2b);
        conv3x3_mfma<CH2, false, 0><<<dim3(3, 12, GB), 256, 0, stream>>>(out2b, wTa1, bfa1, fbuf);
        conv3x3_mfma<CH3, true,  2><<<dim3(3, 12, GB), 256, 0, stream>>>(fbuf, wTa2, bfa2, fxbf);
        conv3x3_mfma<CH2, false, 0><<<dim3(3, 12, GB), 256, 0, stream>>>(out2b, wTp1, bfp1, pp1);
        conv3x3_mfma<CH3, false, 2><<<dim3(3, 12, GB), 256, 0, stream>>>(pp1, wTp2, bfp2, pp2);
        pminmax<<<dim3(128, GB), 256, 0, stream>>>(pp2, (unsigned*)pmm);
        einsum_part<<<dim3(NKC, GB), 256, 0, stream>>>(pp2, fxbf, pmm, pxpart);
        px_reduce<<<(GB * EL_PX + 255) / 256, 256, 0, stream>>>(pxpart, px, GB);
        fc_k<<<GB * 64, 256, 0, stream>>>(px, fc_w, fc_b, outp, b0);
    }
}